// Round 3
// baseline (2734.384 us; speedup 1.0000x reference)
//
#include <hip/hip_runtime.h>

// GNN_19971597927185 — MFMA (bf16 hi/lo split ≈ fp32 accuracy) version.
// B=128, U=64, A=64. One workgroup (4 waves) per (b,a) fiber; wave w owns
// output rows [16w,16w+16), 4 col-tiles over u. post_users via in-register
// rowsum (16-lane shuffle) on the MFMA C-layout (col=lane&15, row=quad*4+reg).
// Intermediates r/msgs in HBM as packed u32 [hi bf16 | lo bf16], layout [u][c].
// S (antenna sum) accumulated by fp32 atomics in the phi epilogue.

typedef __attribute__((ext_vector_type(8))) short bf16x8;
typedef __attribute__((ext_vector_type(4))) float f32x4;
typedef unsigned int u32;

__device__ __forceinline__ u32 bf16_rne(float x) {
    u32 u = __float_as_uint(x);
    return (u + 0x7fffu + ((u >> 16) & 1u)) >> 16;
}
__device__ __forceinline__ float dec_packed(u32 w) {
    // value = hi (bits 15:0 as bf16) + lo (bits 31:16 as bf16)
    return __uint_as_float(w << 16) + __uint_as_float(w & 0xffff0000u);
}
__device__ __forceinline__ u32 pack_hl(float v) {
    u32 hb = bf16_rne(v);
    u32 lb = bf16_rne(v - __uint_as_float(hb << 16));
    return hb | (lb << 16);
}

// ---------------------------------------------------------------- prep ----
// Packs all weights into MFMA A-fragment streams (hi/lo bf16 planes),
// builds w0 rank-1 vectors, transposes cg -> cgT[b][a][u].
__global__ __launch_bounds__(256) void prep_kernel(
    const float* __restrict__ cg, float* __restrict__ cgT,
    unsigned short* __restrict__ packs, float* __restrict__ w0s,
    const float* __restrict__ phi1_W1, const float* __restrict__ phi1_W2,
    const float* __restrict__ phiK_W1, const float* __restrict__ phiK_W2,
    const float* __restrict__ g1_W1,   const float* __restrict__ g1_W2,
    const float* __restrict__ gK_W1,   const float* __restrict__ gK_W2,
    const float* __restrict__ g5_W1)
{
    const int bid = blockIdx.x;
    const int t = threadIdx.x;
    if (bid < 352) {
        int tid = bid * 256 + t;          // 0..90111 weight elements
        int layer, rem, nch;
        if (tid < 57344) { layer = tid >> 12; rem = tid & 4095; nch = 2; }
        else { layer = 14 + ((tid - 57344) >> 13); rem = (tid - 57344) & 8191; nch = 4; }
        const float* src; int stride, colOff; size_t dstBase;
        switch (layer) {
            case 0:  src = phi1_W2;                      stride = 64;  colOff = 0; dstBase = 0; break;
            case 1: case 2: case 3: case 4: {
                int k = layer - 1; src = phiK_W1 + k * 4160; stride = 65; colOff = 1;
                dstBase = 8192 + (size_t)k * 8192; break; }
            case 5: case 6: case 7: case 8: {
                int k = layer - 5; src = phiK_W2 + k * 4096; stride = 64; colOff = 0;
                dstBase = 40960 + (size_t)k * 8192; break; }
            case 9:  src = g1_W1;                        stride = 65;  colOff = 1; dstBase = 73728; break;
            case 10: src = g1_W2;                        stride = 64;  colOff = 0; dstBase = 81920; break;
            case 11: case 12: case 13: {
                int k = layer - 11; src = gK_W2 + k * 4096; stride = 64; colOff = 0;
                dstBase = 139264 + (size_t)k * 8192; break; }
            case 14: case 15: case 16: {
                int k = layer - 14; src = gK_W1 + k * 8192; stride = 128; colOff = 0;
                dstBase = 90112 + (size_t)k * 16384; break; }
            default: src = g5_W1;                        stride = 128; colOff = 0; dstBase = 163840; break;
        }
        int j = rem & 7;
        int lane = (rem >> 3) & 63;
        int rc = rem >> 9;                 // rb*nch + ch
        int rb = rc / nch;
        int ch = rc - rb * nch;
        int o = 16 * rb + (lane & 15);
        int c = colOff + ch * 32 + (lane >> 4) * 8 + j;
        float wv = src[o * stride + c];
        u32 hb = bf16_rne(wv);
        float lo = wv - __uint_as_float(hb << 16);
        u32 lb = bf16_rne(lo);
        size_t base = dstBase + (size_t)rc * 1024 + lane * 8 + j;
        packs[base] = (unsigned short)hb;
        packs[base + 512] = (unsigned short)lb;
    } else if (bid < 354) {
        int i = (bid - 352) * 256 + t;
        if (i < 64)       w0s[i] = phi1_W1[i * 2] + phi1_W1[i * 2 + 1];
        else if (i < 320) { int k = (i - 64) >> 6; int o = (i - 64) & 63; w0s[i] = phiK_W1[k * 4160 + o * 65]; }
        else if (i < 384) { int o = i - 320; w0s[i] = g1_W1[o * 65]; }
    } else {
        int idx = (bid - 354) * 256 + t;   // (b, a, u)
        int b = idx >> 12;
        int u = idx & 63;
        cgT[idx] = cg[((b << 6) + u) * 64 + ((idx >> 6) & 63)];
    }
}

// -------------------------------------------------------- MFMA helpers ----
template <int NCH, int SROW>
__device__ __forceinline__ void mfma_layer(const unsigned short* __restrict__ A,
                                           const unsigned short* Xhi, const unsigned short* Xlo,
                                           int lane, int wv, f32x4 acc[4]) {
    const int n16 = lane & 15, q4 = lane >> 4;
#pragma unroll
    for (int ch = 0; ch < NCH; ++ch) {
        bf16x8 Ah = *(const bf16x8*)(A + ((size_t)(wv * NCH + ch) * 2) * 512 + lane * 8);
        bf16x8 Al = *(const bf16x8*)(A + ((size_t)(wv * NCH + ch) * 2 + 1) * 512 + lane * 8);
#pragma unroll
        for (int tt = 0; tt < 4; ++tt) {
            int boff = (16 * tt + n16) * SROW + ch * 32 + q4 * 8;
            bf16x8 Bh = *(const bf16x8*)(Xhi + boff);
            bf16x8 Bl = *(const bf16x8*)(Xlo + boff);
            acc[tt] = __builtin_amdgcn_mfma_f32_16x16x32_bf16(Ah, Bh, acc[tt], 0, 0, 0);
            acc[tt] = __builtin_amdgcn_mfma_f32_16x16x32_bf16(Ah, Bl, acc[tt], 0, 0, 0);
            acc[tt] = __builtin_amdgcn_mfma_f32_16x16x32_bf16(Al, Bh, acc[tt], 0, 0, 0);
        }
    }
}

__device__ __forceinline__ void post_users_regs(f32x4 acc[4], int wv) {
    constexpr float inv63 = 1.0f / 63.0f;
#pragma unroll
    for (int r = 0; r < 4; ++r) {
        float s = acc[0][r] + acc[1][r] + acc[2][r] + acc[3][r];
        s += __shfl_xor(s, 1);
        s += __shfl_xor(s, 2);
        s += __shfl_xor(s, 4);
        s += __shfl_xor(s, 8);
        if (wv >= 2) {      // rows >= 32: aggregated half (wave-uniform branch)
#pragma unroll
            for (int tt = 0; tt < 4; ++tt) acc[tt][r] = (s - acc[tt][r]) * inv63;
        }
    }
}

template <int SROW>
__device__ __forceinline__ void stage_h(const f32x4 acc[4], unsigned short* Xhi,
                                        unsigned short* Xlo, int lane, int wv) {
    const int n16 = lane & 15, q4 = lane >> 4;
#pragma unroll
    for (int tt = 0; tt < 4; ++tt) {
        u32 hb[4], lb[4];
#pragma unroll
        for (int r = 0; r < 4; ++r) {
            float v = acc[tt][r];
            hb[r] = bf16_rne(v);
            lb[r] = bf16_rne(v - __uint_as_float(hb[r] << 16));
        }
        int off = (16 * tt + n16) * SROW + 16 * wv + 4 * q4;
        *(uint2*)(Xhi + off) = make_uint2(hb[0] | (hb[1] << 16), hb[2] | (hb[3] << 16));
        *(uint2*)(Xlo + off) = make_uint2(lb[0] | (lb[1] << 16), lb[2] | (lb[3] << 16));
    }
}

// ----------------------------------------------------------- main iter ----
// KMF: MFMA K of layer-1 (0 = rank-1 only). HASR: stage r at plane cols 0..63.
// CG: rank-1 cg term (W1 col 0). AGG: stage agg=(S-m)/63 at cols KMF-64..KMF-1.
// PHI_OUT: phi epilogue (post only, write msgs + atomic S).
// FINAL: gamma5 (layer-2 = 1-row dot, write fp32 out).
template <int KMF, bool HASR, bool CG, bool AGG, bool PHI_OUT, bool FINAL>
__global__ __launch_bounds__(256) void iter_kernel(
    const float* __restrict__ cgT, const u32* __restrict__ rIn,
    const u32* __restrict__ mIn, const float* __restrict__ Sin,
    const unsigned short* __restrict__ A1, const float* __restrict__ w0,
    const float* __restrict__ b1,
    const unsigned short* __restrict__ A2, const float* __restrict__ b2,
    const float* __restrict__ w2raw, const float* __restrict__ b2raw,
    u32* __restrict__ outPack, float* __restrict__ outF,
    float* __restrict__ Satom)
{
    constexpr int SROW = (KMF > 64) ? 136 : 72;   // odd multiple of 8 x16B rows
    __shared__ __align__(16) unsigned short Xhi[64 * SROW];
    __shared__ __align__(16) unsigned short Xlo[64 * SROW];
    const int t = threadIdx.x;
    const u32 sb = blockIdx.x;          // slab = (b_local, a)
    const u32 bloc = sb >> 6;
    constexpr float inv63 = 1.0f / 63.0f;

    if constexpr (HASR) {
        const u32* rs = rIn + (size_t)sb * 4096;
#pragma unroll
        for (int q = 0; q < 4; ++q) {
            int grp = q * 256 + t;
            int u = grp >> 4, c4 = (grp & 15) * 4;
            uint4 wd = *(const uint4*)(rs + u * 64 + c4);
            u32 h0 = __builtin_amdgcn_perm(wd.y, wd.x, 0x05040100u);
            u32 h1 = __builtin_amdgcn_perm(wd.w, wd.z, 0x05040100u);
            u32 l0 = __builtin_amdgcn_perm(wd.y, wd.x, 0x07060302u);
            u32 l1 = __builtin_amdgcn_perm(wd.w, wd.z, 0x07060302u);
            int off = u * SROW + c4;
            *(uint2*)(Xhi + off) = make_uint2(h0, h1);
            *(uint2*)(Xlo + off) = make_uint2(l0, l1);
        }
    }
    if constexpr (AGG) {
        const u32* ms = mIn + (size_t)sb * 4096;
        const float* Ss = Sin + (size_t)bloc * 4096;
        constexpr int cb = (KMF == 128) ? 64 : 0;
#pragma unroll
        for (int q = 0; q < 4; ++q) {
            int grp = q * 256 + t;
            int u = grp >> 4, c4 = (grp & 15) * 4;
            uint4 mw = *(const uint4*)(ms + u * 64 + c4);
            float4 sv = *(const float4*)(Ss + u * 64 + c4);
            float a0 = (sv.x - dec_packed(mw.x)) * inv63;
            float a1 = (sv.y - dec_packed(mw.y)) * inv63;
            float a2 = (sv.z - dec_packed(mw.z)) * inv63;
            float a3 = (sv.w - dec_packed(mw.w)) * inv63;
            u32 hb0 = bf16_rne(a0), hb1 = bf16_rne(a1), hb2 = bf16_rne(a2), hb3 = bf16_rne(a3);
            u32 lb0 = bf16_rne(a0 - __uint_as_float(hb0 << 16));
            u32 lb1 = bf16_rne(a1 - __uint_as_float(hb1 << 16));
            u32 lb2 = bf16_rne(a2 - __uint_as_float(hb2 << 16));
            u32 lb3 = bf16_rne(a3 - __uint_as_float(hb3 << 16));
            int off = u * SROW + cb + c4;
            *(uint2*)(Xhi + off) = make_uint2(hb0 | (hb1 << 16), hb2 | (hb3 << 16));
            *(uint2*)(Xlo + off) = make_uint2(lb0 | (lb1 << 16), lb2 | (lb3 << 16));
        }
    }
    __syncthreads();

    const int lane = t & 63;
    const int wv = t >> 6;
    const int n16 = lane & 15, q4 = lane >> 4;

    f32x4 acc[4];
    {
        const float4 bv = *(const float4*)(b1 + 16 * wv + 4 * q4);
#pragma unroll
        for (int tt = 0; tt < 4; ++tt) { acc[tt][0] = bv.x; acc[tt][1] = bv.y; acc[tt][2] = bv.z; acc[tt][3] = bv.w; }
    }
    if constexpr (CG) {
        const float4 w0v = *(const float4*)(w0 + 16 * wv + 4 * q4);
#pragma unroll
        for (int tt = 0; tt < 4; ++tt) {
            float cgv = cgT[(size_t)sb * 64 + 16 * tt + n16];
            acc[tt][0] += w0v.x * cgv; acc[tt][1] += w0v.y * cgv;
            acc[tt][2] += w0v.z * cgv; acc[tt][3] += w0v.w * cgv;
        }
    }
    if constexpr (KMF > 0) mfma_layer<KMF / 32, SROW>(A1, Xhi, Xlo, lane, wv, acc);

#pragma unroll
    for (int tt = 0; tt < 4; ++tt)
#pragma unroll
        for (int r = 0; r < 4; ++r) acc[tt][r] = fmaxf(acc[tt][r], 0.0f);
    post_users_regs(acc, wv);

    __syncthreads();                       // everyone done reading layer-1 B
    stage_h<SROW>(acc, Xhi, Xlo, lane, wv);
    __syncthreads();

    if constexpr (!FINAL) {
        f32x4 acc2[4];
        {
            const float4 bv = *(const float4*)(b2 + 16 * wv + 4 * q4);
#pragma unroll
            for (int tt = 0; tt < 4; ++tt) { acc2[tt][0] = bv.x; acc2[tt][1] = bv.y; acc2[tt][2] = bv.z; acc2[tt][3] = bv.w; }
        }
        mfma_layer<2, SROW>(A2, Xhi, Xlo, lane, wv, acc2);
        if constexpr (!PHI_OUT) {          // gamma: relu before post_users
#pragma unroll
            for (int tt = 0; tt < 4; ++tt)
#pragma unroll
                for (int r = 0; r < 4; ++r) acc2[tt][r] = fmaxf(acc2[tt][r], 0.0f);
        }
        post_users_regs(acc2, wv);

        u32* os = outPack + (size_t)sb * 4096;
#pragma unroll
        for (int tt = 0; tt < 4; ++tt) {
            u32 wbuf[4];
            float vals[4];
#pragma unroll
            for (int r = 0; r < 4; ++r) {
                vals[r] = acc2[tt][r];
                wbuf[r] = pack_hl(vals[r]);
            }
            int oidx = (16 * tt + n16) * 64 + 16 * wv + 4 * q4;
            *(uint4*)(os + oidx) = make_uint4(wbuf[0], wbuf[1], wbuf[2], wbuf[3]);
            if constexpr (PHI_OUT) {
                float* Sb = Satom + (size_t)bloc * 4096;
#pragma unroll
                for (int r = 0; r < 4; ++r) atomicAdd(&Sb[oidx + r], vals[r]);
            }
        }
    } else {
        __shared__ float part[4][64];
        const int cb2 = 16 * wv;
        const unsigned short* hr = Xhi + lane * SROW + cb2;
        const unsigned short* lr = Xlo + lane * SROW + cb2;
        bf16x8 h0 = *(const bf16x8*)hr;
        bf16x8 h1 = *(const bf16x8*)(hr + 8);
        bf16x8 l0 = *(const bf16x8*)lr;
        bf16x8 l1 = *(const bf16x8*)(lr + 8);
        float sum = 0.0f;
#pragma unroll
        for (int j = 0; j < 8; ++j) {
            float v0 = __uint_as_float(((u32)(unsigned short)h0[j]) << 16)
                     + __uint_as_float(((u32)(unsigned short)l0[j]) << 16);
            float v1 = __uint_as_float(((u32)(unsigned short)h1[j]) << 16)
                     + __uint_as_float(((u32)(unsigned short)l1[j]) << 16);
            sum += w2raw[cb2 + j] * v0;
            sum += w2raw[cb2 + 8 + j] * v1;
        }
        part[wv][lane] = sum;
        __syncthreads();
        if (t < 64) {
            float o = b2raw[0] + part[0][t] + part[1][t] + part[2][t] + part[3][t];
            outF[((size_t)bloc * 64 + t) * 64 + (sb & 63)] = o;
        }
    }
}

// -------------------------------------------------------------- launch ----
extern "C" void kernel_launch(void* const* d_in, const int* in_sizes, int n_in,
                              void* d_out, int out_size, void* d_ws, size_t ws_size,
                              hipStream_t stream) {
    const float* cg      = (const float*)d_in[0];
    const float* phi1_W1 = (const float*)d_in[1];
    const float* phi1_b1 = (const float*)d_in[2];
    const float* phi1_W2 = (const float*)d_in[3];
    const float* phi1_b2 = (const float*)d_in[4];
    const float* phiK_W1 = (const float*)d_in[5];
    const float* phiK_b1 = (const float*)d_in[6];
    const float* phiK_W2 = (const float*)d_in[7];
    const float* phiK_b2 = (const float*)d_in[8];
    const float* g1_W1   = (const float*)d_in[9];
    const float* g1_b1   = (const float*)d_in[10];
    const float* g1_W2   = (const float*)d_in[11];
    const float* g1_b2   = (const float*)d_in[12];
    const float* gK_W1   = (const float*)d_in[13];
    const float* gK_b1   = (const float*)d_in[14];
    const float* gK_W2   = (const float*)d_in[15];
    const float* gK_b2   = (const float*)d_in[16];
    const float* g5_W1   = (const float*)d_in[17];
    const float* g5_b1   = (const float*)d_in[18];
    const float* g5_W2   = (const float*)d_in[19];
    const float* g5_b2   = (const float*)d_in[20];
    (void)in_sizes; (void)n_in; (void)out_size;

    // Chunk over batch: per-b footprint = r(262144) + msgs(262144) + S(4096) u32.
    int BC = 128;
    while (BC > 4 && ((size_t)BC * 528384 + 614784) * 4 > ws_size) BC >>= 1;
    const int NC = 128 / BC;

    u32*   ws    = (u32*)d_ws;
    u32*   r     = ws;
    u32*   msgs  = r + (size_t)BC * 262144;
    float* S     = (float*)(msgs + (size_t)BC * 262144);
    float* cgT   = S + (size_t)BC * 4096;
    unsigned short* Apack = (unsigned short*)(cgT + 524288);
    float* w0s   = (float*)(Apack + 180224);
    float* out   = (float*)d_out;

    prep_kernel<<<354 + 2048, 256, 0, stream>>>(cg, cgT, Apack, w0s,
        phi1_W1, phi1_W2, phiK_W1, phiK_W2, g1_W1, g1_W2, gK_W1, gK_W2, g5_W1);

    const int nblk = BC * 64;
    const size_t Sbytes = (size_t)BC * 4096 * 4;

    for (int c = 0; c < NC; ++c) {
        const float* cgTc = cgT + (size_t)c * BC * 4096;
        float* outc = out + (size_t)c * BC * 4096;

        hipMemsetAsync(S, 0, Sbytes, stream);
        // phi1: L1 rank-1 (cg,cg), L2 MFMA; writes msgs + S
        iter_kernel<0, false, true, false, true, false><<<nblk, 256, 0, stream>>>(
            cgTc, nullptr, nullptr, nullptr,
            nullptr, w0s, phi1_b1, Apack + 0, phi1_b2,
            nullptr, nullptr, msgs, nullptr, S);
        // gamma1: [cg | agg], K=64 MFMA over agg + rank-1 cg; writes r
        iter_kernel<64, false, true, true, false, false><<<nblk, 256, 0, stream>>>(
            cgTc, nullptr, msgs, S,
            Apack + 73728, w0s + 320, g1_b1, Apack + 81920, g1_b2,
            nullptr, nullptr, r, nullptr, nullptr);

        for (int k = 0; k < 4; ++k) {
            hipMemsetAsync(S, 0, Sbytes, stream);
            // phiK: [cg | r], K=64 MFMA over r + rank-1 cg; writes msgs + S
            iter_kernel<64, true, true, false, true, false><<<nblk, 256, 0, stream>>>(
                cgTc, r, nullptr, nullptr,
                Apack + 8192 + (size_t)k * 8192, w0s + 64 + k * 64, phiK_b1 + k * 64,
                Apack + 40960 + (size_t)k * 8192, phiK_b2 + k * 64,
                nullptr, nullptr, msgs, nullptr, S);
            if (k < 3) {
                // gammaK: [r | agg], K=128; writes r (in place)
                iter_kernel<128, true, false, true, false, false><<<nblk, 256, 0, stream>>>(
                    nullptr, r, msgs, S,
                    Apack + 90112 + (size_t)k * 16384, nullptr, gK_b1 + k * 64,
                    Apack + 139264 + (size_t)k * 8192, gK_b2 + k * 64,
                    nullptr, nullptr, r, nullptr, nullptr);
            } else {
                // gamma5: [r | agg], K=128; L2 = 1-row dot; writes fp32 out
                iter_kernel<128, true, false, true, false, true><<<nblk, 256, 0, stream>>>(
                    nullptr, r, msgs, S,
                    Apack + 163840, nullptr, g5_b1,
                    nullptr, nullptr, g5_W2, g5_b2,
                    nullptr, outc, nullptr);
            }
        }
    }
}

// Round 4
// 740.917 us; speedup vs baseline: 3.6905x; 3.6905x over previous
//
#include <hip/hip_runtime.h>

// GNN_19971597927185 — MFMA bf16 hi/lo-split compute, low-traffic storage.
// B=128, U=64, A=64. One workgroup (4 waves) per (b,a) fiber; wave wv owns
// output rows [16wv,16wv+16), 4 col-tiles over u.
// Storage: msgs = bf16 [u][c] (64x64 per slab); r = two bf16 planes (hi, lo),
// [u][c] per slab. S[b][u][c] fp32 from a separate reduce kernel (no atomics).
// phi reads only rHi (accuracy: its output is attenuated by /63 aggregation);
// gamma reads rHi+rLo (feats accuracy reaches the output directly).

typedef __attribute__((ext_vector_type(8))) short bf16x8;
typedef __attribute__((ext_vector_type(4))) float f32x4;
typedef unsigned int u32;
typedef unsigned short u16;

__device__ __forceinline__ u32 bf16_rne(float x) {
    u32 u = __float_as_uint(x);
    return (u + 0x7fffu + ((u >> 16) & 1u)) >> 16;
}
__device__ __forceinline__ float bflo(u32 w) { return __uint_as_float(w << 16); }
__device__ __forceinline__ float bfhi(u32 w) { return __uint_as_float(w & 0xffff0000u); }

// ---------------------------------------------------------------- prep ----
// Packs all weights into MFMA A-fragment streams (hi/lo bf16 planes),
// builds w0 rank-1 vectors, transposes cg -> cgT[b][a][u].
__global__ __launch_bounds__(256) void prep_kernel(
    const float* __restrict__ cg, float* __restrict__ cgT,
    u16* __restrict__ packs, float* __restrict__ w0s,
    const float* __restrict__ phi1_W1, const float* __restrict__ phi1_W2,
    const float* __restrict__ phiK_W1, const float* __restrict__ phiK_W2,
    const float* __restrict__ g1_W1,   const float* __restrict__ g1_W2,
    const float* __restrict__ gK_W1,   const float* __restrict__ gK_W2,
    const float* __restrict__ g5_W1)
{
    const int bid = blockIdx.x;
    const int t = threadIdx.x;
    if (bid < 352) {
        int tid = bid * 256 + t;          // 0..90111 weight elements
        int layer, rem, nch;
        if (tid < 57344) { layer = tid >> 12; rem = tid & 4095; nch = 2; }
        else { layer = 14 + ((tid - 57344) >> 13); rem = (tid - 57344) & 8191; nch = 4; }
        const float* src; int stride, colOff; size_t dstBase;
        switch (layer) {
            case 0:  src = phi1_W2;                      stride = 64;  colOff = 0; dstBase = 0; break;
            case 1: case 2: case 3: case 4: {
                int k = layer - 1; src = phiK_W1 + k * 4160; stride = 65; colOff = 1;
                dstBase = 8192 + (size_t)k * 8192; break; }
            case 5: case 6: case 7: case 8: {
                int k = layer - 5; src = phiK_W2 + k * 4096; stride = 64; colOff = 0;
                dstBase = 40960 + (size_t)k * 8192; break; }
            case 9:  src = g1_W1;                        stride = 65;  colOff = 1; dstBase = 73728; break;
            case 10: src = g1_W2;                        stride = 64;  colOff = 0; dstBase = 81920; break;
            case 11: case 12: case 13: {
                int k = layer - 11; src = gK_W2 + k * 4096; stride = 64; colOff = 0;
                dstBase = 139264 + (size_t)k * 8192; break; }
            case 14: case 15: case 16: {
                int k = layer - 14; src = gK_W1 + k * 8192; stride = 128; colOff = 0;
                dstBase = 90112 + (size_t)k * 16384; break; }
            default: src = g5_W1;                        stride = 128; colOff = 0; dstBase = 163840; break;
        }
        int j = rem & 7;
        int lane = (rem >> 3) & 63;
        int rc = rem >> 9;                 // rb*nch + ch
        int rb = rc / nch;
        int ch = rc - rb * nch;
        int o = 16 * rb + (lane & 15);
        int c = colOff + ch * 32 + (lane >> 4) * 8 + j;
        float wv = src[o * stride + c];
        u32 hb = bf16_rne(wv);
        u32 lb = bf16_rne(wv - bflo(hb));
        size_t base = dstBase + (size_t)rc * 1024 + lane * 8 + j;
        packs[base] = (u16)hb;
        packs[base + 512] = (u16)lb;
    } else if (bid < 354) {
        int i = (bid - 352) * 256 + t;
        if (i < 64)       w0s[i] = phi1_W1[i * 2] + phi1_W1[i * 2 + 1];
        else if (i < 320) { int k = (i - 64) >> 6; int o = (i - 64) & 63; w0s[i] = phiK_W1[k * 4160 + o * 65]; }
        else if (i < 384) { int o = i - 320; w0s[i] = g1_W1[o * 65]; }
    } else {
        int idx = (bid - 354) * 256 + t;   // (b, a, u)
        int b = idx >> 12;
        int u = idx & 63;
        cgT[idx] = cg[((b << 6) + u) * 64 + ((idx >> 6) & 63)];
    }
}

// -------------------------------------------------------- MFMA helpers ----
// LO: B has a lo plane (3-MFMA per tile); else 2-MFMA (Bh only).
template <int NCH, int SROW, bool LO>
__device__ __forceinline__ void mfma_layer(const u16* __restrict__ A,
                                           const u16* Xhi, const u16* Xlo,
                                           int lane, int wv, f32x4 acc[4]) {
    const int n16 = lane & 15, q4 = lane >> 4;
#pragma unroll
    for (int ch = 0; ch < NCH; ++ch) {
        bf16x8 Ah = *(const bf16x8*)(A + ((size_t)(wv * NCH + ch) * 2) * 512 + lane * 8);
        bf16x8 Al = *(const bf16x8*)(A + ((size_t)(wv * NCH + ch) * 2 + 1) * 512 + lane * 8);
#pragma unroll
        for (int tt = 0; tt < 4; ++tt) {
            int boff = (16 * tt + n16) * SROW + ch * 32 + q4 * 8;
            bf16x8 Bh = *(const bf16x8*)(Xhi + boff);
            acc[tt] = __builtin_amdgcn_mfma_f32_16x16x32_bf16(Ah, Bh, acc[tt], 0, 0, 0);
            acc[tt] = __builtin_amdgcn_mfma_f32_16x16x32_bf16(Al, Bh, acc[tt], 0, 0, 0);
            if constexpr (LO) {
                bf16x8 Bl = *(const bf16x8*)(Xlo + boff);
                acc[tt] = __builtin_amdgcn_mfma_f32_16x16x32_bf16(Ah, Bl, acc[tt], 0, 0, 0);
            }
        }
    }
}

__device__ __forceinline__ void post_users_regs(f32x4 acc[4], int wv) {
    constexpr float inv63 = 1.0f / 63.0f;
#pragma unroll
    for (int r = 0; r < 4; ++r) {
        float s = acc[0][r] + acc[1][r] + acc[2][r] + acc[3][r];
        s += __shfl_xor(s, 1);
        s += __shfl_xor(s, 2);
        s += __shfl_xor(s, 4);
        s += __shfl_xor(s, 8);
        if (wv >= 2) {      // rows >= 32: aggregated half (wave-uniform branch)
#pragma unroll
            for (int tt = 0; tt < 4; ++tt) acc[tt][r] = (s - acc[tt][r]) * inv63;
        }
    }
}

template <int SROW>
__device__ __forceinline__ void stage_h(const f32x4 acc[4], u16* Xhi,
                                        u16* Xlo, int lane, int wv) {
    const int n16 = lane & 15, q4 = lane >> 4;
#pragma unroll
    for (int tt = 0; tt < 4; ++tt) {
        u32 hb[4], lb[4];
#pragma unroll
        for (int r = 0; r < 4; ++r) {
            float v = acc[tt][r];
            hb[r] = bf16_rne(v);
            lb[r] = bf16_rne(v - bflo(hb[r]));
        }
        int off = (16 * tt + n16) * SROW + 16 * wv + 4 * q4;
        *(uint2*)(Xhi + off) = make_uint2(hb[0] | (hb[1] << 16), hb[2] | (hb[3] << 16));
        *(uint2*)(Xlo + off) = make_uint2(lb[0] | (lb[1] << 16), lb[2] | (lb[3] << 16));
    }
}

// -------------------------------------------------------------- reduce ----
// S[b][u][c] (fp32) = sum_a msgs[b,a][u][c] (bf16). Thread = one u32 (2 c's).
__global__ __launch_bounds__(256) void reduce_kernel(
    const u32* __restrict__ msgs, float* __restrict__ S)
{
    int idx = blockIdx.x * 256 + threadIdx.x;   // b*2048 + j
    int b = idx >> 11;
    int j = idx & 2047;
    const u32* p = msgs + (size_t)b * 131072 + j;
    float s0 = 0.0f, s1 = 0.0f;
#pragma unroll 8
    for (int a = 0; a < 64; ++a) {
        u32 w = p[(size_t)a * 2048];
        s0 += bflo(w);
        s1 += bfhi(w);
    }
    *(float2*)(S + (size_t)b * 4096 + 2 * j) = make_float2(s0, s1);
}

// ----------------------------------------------------------- main iter ----
// KMF: layer-1 MFMA K (0 = rank-1 only). HASR: r staged at cols 0..63
// (hi always; lo too iff !PHI_OUT). CG: rank-1 cg term. AGG: agg staged at
// cols (KMF==128 ? 64.. : 0..). PHI_OUT: phi epilogue (no relu before post,
// write bf16 msgs). FINAL: gamma5 (layer-2 = 1-row dot, fp32 out).
template <int KMF, bool HASR, bool CG, bool AGG, bool PHI_OUT, bool FINAL>
__global__ __launch_bounds__(256) void iter_kernel(
    const float* __restrict__ cgT,
    const u16* __restrict__ rInHi, const u16* __restrict__ rInLo,
    const u32* __restrict__ mIn, const float* __restrict__ Sin,
    const u16* __restrict__ A1, const float* __restrict__ w0,
    const float* __restrict__ b1,
    const u16* __restrict__ A2, const float* __restrict__ b2,
    const float* __restrict__ w2raw, const float* __restrict__ b2raw,
    u16* __restrict__ outHi, u16* __restrict__ outLo, float* __restrict__ outF)
{
    constexpr int SROW = (KMF > 64) ? 136 : 72;   // 16B-aligned rows
    constexpr bool LO1 = !PHI_OUT;                // gamma layer-1 B has lo plane
    __shared__ __align__(16) u16 Xhi[64 * SROW];
    __shared__ __align__(16) u16 Xlo[64 * SROW];
    const int t = threadIdx.x;
    const u32 sb = blockIdx.x;          // slab = (b_local, a)
    const u32 bloc = sb >> 6;
    constexpr float inv63 = 1.0f / 63.0f;

    if constexpr (HASR) {
        const u16* rsH = rInHi + (size_t)sb * 4096;
#pragma unroll
        for (int q = 0; q < 2; ++q) {
            int grp = q * 256 + t;
            int u = grp >> 3, c8 = (grp & 7) * 8;
            *(uint4*)(Xhi + u * SROW + c8) = *(const uint4*)(rsH + u * 64 + c8);
        }
        if constexpr (LO1) {
            const u16* rsL = rInLo + (size_t)sb * 4096;
#pragma unroll
            for (int q = 0; q < 2; ++q) {
                int grp = q * 256 + t;
                int u = grp >> 3, c8 = (grp & 7) * 8;
                *(uint4*)(Xlo + u * SROW + c8) = *(const uint4*)(rsL + u * 64 + c8);
            }
        }
    }
    if constexpr (AGG) {
        const u32* ms = mIn + (size_t)sb * 2048;
        const float* Ss = Sin + (size_t)bloc * 4096;
        constexpr int cb = (KMF == 128) ? 64 : 0;
#pragma unroll
        for (int q = 0; q < 4; ++q) {
            int grp = q * 256 + t;
            int u = grp >> 4, c4 = (grp & 15) * 4;
            uint2 mw = *(const uint2*)(ms + u * 32 + (c4 >> 1));
            float4 sv = *(const float4*)(Ss + u * 64 + c4);
            float a0 = (sv.x - bflo(mw.x)) * inv63;
            float a1 = (sv.y - bfhi(mw.x)) * inv63;
            float a2 = (sv.z - bflo(mw.y)) * inv63;
            float a3 = (sv.w - bfhi(mw.y)) * inv63;
            u32 h0 = bf16_rne(a0), h1 = bf16_rne(a1), h2 = bf16_rne(a2), h3 = bf16_rne(a3);
            u32 l0 = bf16_rne(a0 - bflo(h0));
            u32 l1 = bf16_rne(a1 - bflo(h1));
            u32 l2 = bf16_rne(a2 - bflo(h2));
            u32 l3 = bf16_rne(a3 - bflo(h3));
            int off = u * SROW + cb + c4;
            *(uint2*)(Xhi + off) = make_uint2(h0 | (h1 << 16), h2 | (h3 << 16));
            *(uint2*)(Xlo + off) = make_uint2(l0 | (l1 << 16), l2 | (l3 << 16));
        }
    }
    __syncthreads();

    const int lane = t & 63;
    const int wv = t >> 6;
    const int n16 = lane & 15, q4 = lane >> 4;

    f32x4 acc[4];
    {
        const float4 bv = *(const float4*)(b1 + 16 * wv + 4 * q4);
#pragma unroll
        for (int tt = 0; tt < 4; ++tt) { acc[tt][0] = bv.x; acc[tt][1] = bv.y; acc[tt][2] = bv.z; acc[tt][3] = bv.w; }
    }
    if constexpr (CG) {
        const float4 w0v = *(const float4*)(w0 + 16 * wv + 4 * q4);
#pragma unroll
        for (int tt = 0; tt < 4; ++tt) {
            float cgv = cgT[(size_t)sb * 64 + 16 * tt + n16];
            acc[tt][0] += w0v.x * cgv; acc[tt][1] += w0v.y * cgv;
            acc[tt][2] += w0v.z * cgv; acc[tt][3] += w0v.w * cgv;
        }
    }
    if constexpr (KMF > 0)
        mfma_layer<KMF / 32, SROW, LO1 || AGG>(A1, Xhi, Xlo, lane, wv, acc);

#pragma unroll
    for (int tt = 0; tt < 4; ++tt)
#pragma unroll
        for (int r = 0; r < 4; ++r) acc[tt][r] = fmaxf(acc[tt][r], 0.0f);
    post_users_regs(acc, wv);

    __syncthreads();                       // everyone done reading layer-1 B
    stage_h<SROW>(acc, Xhi, Xlo, lane, wv);
    __syncthreads();

    if constexpr (!FINAL) {
        f32x4 acc2[4];
        {
            const float4 bv = *(const float4*)(b2 + 16 * wv + 4 * q4);
#pragma unroll
            for (int tt = 0; tt < 4; ++tt) { acc2[tt][0] = bv.x; acc2[tt][1] = bv.y; acc2[tt][2] = bv.z; acc2[tt][3] = bv.w; }
        }
        mfma_layer<2, SROW, true>(A2, Xhi, Xlo, lane, wv, acc2);
        if constexpr (!PHI_OUT) {          // gamma: relu before post_users
#pragma unroll
            for (int tt = 0; tt < 4; ++tt)
#pragma unroll
                for (int r = 0; r < 4; ++r) acc2[tt][r] = fmaxf(acc2[tt][r], 0.0f);
        }
        post_users_regs(acc2, wv);

        // Bounce through LDS ([u][c] bf16, row stride 72) for coalesced stores.
        __syncthreads();
#pragma unroll
        for (int tt = 0; tt < 4; ++tt) {
            u32 hb[4], lb[4];
#pragma unroll
            for (int r = 0; r < 4; ++r) {
                float v = acc2[tt][r];
                hb[r] = bf16_rne(v);
                if constexpr (!PHI_OUT) lb[r] = bf16_rne(v - bflo(hb[r]));
            }
            int off = (16 * tt + n16) * 72 + 16 * wv + 4 * q4;
            *(uint2*)(Xhi + off) = make_uint2(hb[0] | (hb[1] << 16), hb[2] | (hb[3] << 16));
            if constexpr (!PHI_OUT)
                *(uint2*)(Xlo + off) = make_uint2(lb[0] | (lb[1] << 16), lb[2] | (lb[3] << 16));
        }
        __syncthreads();
        u16* oH = outHi + (size_t)sb * 4096;
#pragma unroll
        for (int q = 0; q < 2; ++q) {
            int grp = q * 256 + t;
            int u = grp >> 3, c8 = (grp & 7) * 8;
            *(uint4*)(oH + u * 64 + c8) = *(const uint4*)(Xhi + u * 72 + c8);
        }
        if constexpr (!PHI_OUT) {
            u16* oL = outLo + (size_t)sb * 4096;
#pragma unroll
            for (int q = 0; q < 2; ++q) {
                int grp = q * 256 + t;
                int u = grp >> 3, c8 = (grp & 7) * 8;
                *(uint4*)(oL + u * 64 + c8) = *(const uint4*)(Xlo + u * 72 + c8);
            }
        }
    } else {
        __shared__ float part[4][64];
        const int cb2 = 16 * wv;
        const u16* hr = Xhi + lane * SROW + cb2;
        const u16* lr = Xlo + lane * SROW + cb2;
        bf16x8 h0 = *(const bf16x8*)hr;
        bf16x8 h1 = *(const bf16x8*)(hr + 8);
        bf16x8 l0 = *(const bf16x8*)lr;
        bf16x8 l1 = *(const bf16x8*)(lr + 8);
        float sum = 0.0f;
#pragma unroll
        for (int j = 0; j < 8; ++j) {
            float v0 = bflo((u32)(u16)h0[j]) + bflo((u32)(u16)l0[j]);
            float v1 = bflo((u32)(u16)h1[j]) + bflo((u32)(u16)l1[j]);
            sum += w2raw[cb2 + j] * v0;
            sum += w2raw[cb2 + 8 + j] * v1;
        }
        part[wv][lane] = sum;
        __syncthreads();
        if (t < 64) {
            float o = b2raw[0] + part[0][t] + part[1][t] + part[2][t] + part[3][t];
            outF[((size_t)bloc * 64 + t) * 64 + (sb & 63)] = o;
        }
    }
}

// -------------------------------------------------------------- launch ----
extern "C" void kernel_launch(void* const* d_in, const int* in_sizes, int n_in,
                              void* d_out, int out_size, void* d_ws, size_t ws_size,
                              hipStream_t stream) {
    const float* cg      = (const float*)d_in[0];
    const float* phi1_W1 = (const float*)d_in[1];
    const float* phi1_b1 = (const float*)d_in[2];
    const float* phi1_W2 = (const float*)d_in[3];
    const float* phi1_b2 = (const float*)d_in[4];
    const float* phiK_W1 = (const float*)d_in[5];
    const float* phiK_b1 = (const float*)d_in[6];
    const float* phiK_W2 = (const float*)d_in[7];
    const float* phiK_b2 = (const float*)d_in[8];
    const float* g1_W1   = (const float*)d_in[9];
    const float* g1_b1   = (const float*)d_in[10];
    const float* g1_W2   = (const float*)d_in[11];
    const float* g1_b2   = (const float*)d_in[12];
    const float* gK_W1   = (const float*)d_in[13];
    const float* gK_b1   = (const float*)d_in[14];
    const float* gK_W2   = (const float*)d_in[15];
    const float* gK_b2   = (const float*)d_in[16];
    const float* g5_W1   = (const float*)d_in[17];
    const float* g5_b1   = (const float*)d_in[18];
    const float* g5_W2   = (const float*)d_in[19];
    const float* g5_b2   = (const float*)d_in[20];
    (void)in_sizes; (void)n_in; (void)out_size;

    // Footprint (bytes): rHi/rLo/msgs = 3*BC*524288, S = BC*16384,
    // cgT = 2 MB, Apack = 360448, w0s tiny.
    int BC = 128;
    while (BC > 4 && (size_t)BC * 1589248 + 2461696 > ws_size) BC >>= 1;
    const int NC = 128 / BC;

    u16*   rHi  = (u16*)d_ws;
    u16*   rLo  = rHi + (size_t)BC * 262144;
    u16*   msgs = rLo + (size_t)BC * 262144;
    float* S    = (float*)(msgs + (size_t)BC * 262144);
    float* cgT  = S + (size_t)BC * 4096;
    u16*   Apack = (u16*)(cgT + 524288);
    float* w0s  = (float*)(Apack + 180224);
    float* out  = (float*)d_out;

    prep_kernel<<<354 + 2048, 256, 0, stream>>>(cg, cgT, Apack, w0s,
        phi1_W1, phi1_W2, phiK_W1, phiK_W2, g1_W1, g1_W2, gK_W1, gK_W2, g5_W1);

    const int nblk = BC * 64;
    const int rblk = BC * 8;

    for (int c = 0; c < NC; ++c) {
        const float* cgTc = cgT + (size_t)c * BC * 4096;
        float* outc = out + (size_t)c * BC * 4096;

        // phi1: L1 rank-1 (cg,cg), L2 MFMA; writes msgs (bf16)
        iter_kernel<0, false, true, false, true, false><<<nblk, 256, 0, stream>>>(
            cgTc, nullptr, nullptr, nullptr, nullptr,
            nullptr, w0s, phi1_b1, Apack + 0, phi1_b2,
            nullptr, nullptr, msgs, nullptr, nullptr);
        reduce_kernel<<<rblk, 256, 0, stream>>>((const u32*)msgs, S);
        // gamma1: [cg | agg], K=64 + rank-1 cg; writes rHi/rLo
        iter_kernel<64, false, true, true, false, false><<<nblk, 256, 0, stream>>>(
            cgTc, nullptr, nullptr, (const u32*)msgs, S,
            Apack + 73728, w0s + 320, g1_b1, Apack + 81920, g1_b2,
            nullptr, nullptr, rHi, rLo, nullptr);

        for (int k = 0; k < 4; ++k) {
            // phiK: [cg | r(hi-only)], K=64 + rank-1 cg; writes msgs
            iter_kernel<64, true, true, false, true, false><<<nblk, 256, 0, stream>>>(
                cgTc, rHi, nullptr, nullptr, nullptr,
                Apack + 8192 + (size_t)k * 8192, w0s + 64 + k * 64, phiK_b1 + k * 64,
                Apack + 40960 + (size_t)k * 8192, phiK_b2 + k * 64,
                nullptr, nullptr, msgs, nullptr, nullptr);
            reduce_kernel<<<rblk, 256, 0, stream>>>((const u32*)msgs, S);
            if (k < 3) {
                // gammaK: [r | agg], K=128; writes rHi/rLo in place
                iter_kernel<128, true, false, true, false, false><<<nblk, 256, 0, stream>>>(
                    nullptr, rHi, rLo, (const u32*)msgs, S,
                    Apack + 90112 + (size_t)k * 16384, nullptr, gK_b1 + k * 64,
                    Apack + 139264 + (size_t)k * 8192, gK_b2 + k * 64,
                    nullptr, nullptr, rHi, rLo, nullptr);
            } else {
                // gamma5: [r | agg], K=128; L2 = 1-row dot; writes fp32 out
                iter_kernel<128, true, false, true, false, true><<<nblk, 256, 0, stream>>>(
                    nullptr, rHi, rLo, (const u32*)msgs, S,
                    Apack + 163840, nullptr, g5_b1,
                    nullptr, nullptr, g5_W2, g5_b2,
                    nullptr, nullptr, outc);
            }
        }
    }
}

// Round 5
// 709.020 us; speedup vs baseline: 3.8566x; 1.0450x over previous
//
#include <hip/hip_runtime.h>

// GNN_19971597927185 — MFMA bf16 hi/lo-split, fused [gamma_k + phi_{k+1}].
// B=128, U=64, A=64. One workgroup (4 waves) per (b,a) fiber; wave wv owns
// output rows [16wv,16wv+16), 4 col-tiles over u.
// Storage: msgs = bf16 [u][c]; r = two bf16 planes (hi, lo) [u][c];
// S[b][u][c] fp32 via separate reduce kernel (no atomics).
// Fusion: gamma_k computes r_k, stages it in LDS (also written to HBM for the
// next kernel's gamma), then phi_{k+1} runs in the same block reading r_k
// from LDS — saves phi's r read + launch overhead.

typedef __attribute__((ext_vector_type(8))) short bf16x8;
typedef __attribute__((ext_vector_type(4))) float f32x4;
typedef unsigned int u32;
typedef unsigned short u16;

__device__ __forceinline__ u32 bf16_rne(float x) {
    u32 u = __float_as_uint(x);
    return (u + 0x7fffu + ((u >> 16) & 1u)) >> 16;
}
__device__ __forceinline__ float bflo(u32 w) { return __uint_as_float(w << 16); }
__device__ __forceinline__ float bfhi(u32 w) { return __uint_as_float(w & 0xffff0000u); }

// ---------------------------------------------------------------- prep ----
__global__ __launch_bounds__(256) void prep_kernel(
    const float* __restrict__ cg, float* __restrict__ cgT,
    u16* __restrict__ packs, float* __restrict__ w0s,
    const float* __restrict__ phi1_W1, const float* __restrict__ phi1_W2,
    const float* __restrict__ phiK_W1, const float* __restrict__ phiK_W2,
    const float* __restrict__ g1_W1,   const float* __restrict__ g1_W2,
    const float* __restrict__ gK_W1,   const float* __restrict__ gK_W2,
    const float* __restrict__ g5_W1)
{
    const int bid = blockIdx.x;
    const int t = threadIdx.x;
    if (bid < 352) {
        int tid = bid * 256 + t;          // 0..90111 weight elements
        int layer, rem, nch;
        if (tid < 57344) { layer = tid >> 12; rem = tid & 4095; nch = 2; }
        else { layer = 14 + ((tid - 57344) >> 13); rem = (tid - 57344) & 8191; nch = 4; }
        const float* src; int stride, colOff; size_t dstBase;
        switch (layer) {
            case 0:  src = phi1_W2;                      stride = 64;  colOff = 0; dstBase = 0; break;
            case 1: case 2: case 3: case 4: {
                int k = layer - 1; src = phiK_W1 + k * 4160; stride = 65; colOff = 1;
                dstBase = 8192 + (size_t)k * 8192; break; }
            case 5: case 6: case 7: case 8: {
                int k = layer - 5; src = phiK_W2 + k * 4096; stride = 64; colOff = 0;
                dstBase = 40960 + (size_t)k * 8192; break; }
            case 9:  src = g1_W1;                        stride = 65;  colOff = 1; dstBase = 73728; break;
            case 10: src = g1_W2;                        stride = 64;  colOff = 0; dstBase = 81920; break;
            case 11: case 12: case 13: {
                int k = layer - 11; src = gK_W2 + k * 4096; stride = 64; colOff = 0;
                dstBase = 139264 + (size_t)k * 8192; break; }
            case 14: case 15: case 16: {
                int k = layer - 14; src = gK_W1 + k * 8192; stride = 128; colOff = 0;
                dstBase = 90112 + (size_t)k * 16384; break; }
            default: src = g5_W1;                        stride = 128; colOff = 0; dstBase = 163840; break;
        }
        int j = rem & 7;
        int lane = (rem >> 3) & 63;
        int rc = rem >> 9;                 // rb*nch + ch
        int rb = rc / nch;
        int ch = rc - rb * nch;
        int o = 16 * rb + (lane & 15);
        int c = colOff + ch * 32 + (lane >> 4) * 8 + j;
        float wv = src[o * stride + c];
        u32 hb = bf16_rne(wv);
        u32 lb = bf16_rne(wv - bflo(hb));
        size_t base = dstBase + (size_t)rc * 1024 + lane * 8 + j;
        packs[base] = (u16)hb;
        packs[base + 512] = (u16)lb;
    } else if (bid < 354) {
        int i = (bid - 352) * 256 + t;
        if (i < 64)       w0s[i] = phi1_W1[i * 2] + phi1_W1[i * 2 + 1];
        else if (i < 320) { int k = (i - 64) >> 6; int o = (i - 64) & 63; w0s[i] = phiK_W1[k * 4160 + o * 65]; }
        else if (i < 384) { int o = i - 320; w0s[i] = g1_W1[o * 65]; }
    } else {
        int idx = (bid - 354) * 256 + t;   // (b, a, u)
        int b = idx >> 12;
        int u = idx & 63;
        cgT[idx] = cg[((b << 6) + u) * 64 + ((idx >> 6) & 63)];
    }
}

// -------------------------------------------------------- MFMA helpers ----
// LO: B has a lo plane (3-MFMA); CB: column offset of B in the X buffer.
template <int NCH, int SROW, bool LO, int CB>
__device__ __forceinline__ void mfma_layer(const u16* __restrict__ A,
                                           const u16* Xhi, const u16* Xlo,
                                           int lane, int wv, f32x4 acc[4]) {
    const int n16 = lane & 15, q4 = lane >> 4;
#pragma unroll
    for (int ch = 0; ch < NCH; ++ch) {
        bf16x8 Ah = *(const bf16x8*)(A + ((size_t)(wv * NCH + ch) * 2) * 512 + lane * 8);
        bf16x8 Al = *(const bf16x8*)(A + ((size_t)(wv * NCH + ch) * 2 + 1) * 512 + lane * 8);
#pragma unroll
        for (int tt = 0; tt < 4; ++tt) {
            int boff = (16 * tt + n16) * SROW + CB + ch * 32 + q4 * 8;
            bf16x8 Bh = *(const bf16x8*)(Xhi + boff);
            acc[tt] = __builtin_amdgcn_mfma_f32_16x16x32_bf16(Ah, Bh, acc[tt], 0, 0, 0);
            acc[tt] = __builtin_amdgcn_mfma_f32_16x16x32_bf16(Al, Bh, acc[tt], 0, 0, 0);
            if constexpr (LO) {
                bf16x8 Bl = *(const bf16x8*)(Xlo + boff);
                acc[tt] = __builtin_amdgcn_mfma_f32_16x16x32_bf16(Ah, Bl, acc[tt], 0, 0, 0);
            }
        }
    }
}

__device__ __forceinline__ void post_users_regs(f32x4 acc[4], int wv) {
    constexpr float inv63 = 1.0f / 63.0f;
#pragma unroll
    for (int r = 0; r < 4; ++r) {
        float s = acc[0][r] + acc[1][r] + acc[2][r] + acc[3][r];
        s += __shfl_xor(s, 1);
        s += __shfl_xor(s, 2);
        s += __shfl_xor(s, 4);
        s += __shfl_xor(s, 8);
        if (wv >= 2) {      // rows >= 32: aggregated half (wave-uniform branch)
#pragma unroll
            for (int tt = 0; tt < 4; ++tt) acc[tt][r] = (s - acc[tt][r]) * inv63;
        }
    }
}

template <int SROW, int CB>
__device__ __forceinline__ void stage_h(const f32x4 acc[4], u16* Xhi,
                                        u16* Xlo, int lane, int wv) {
    const int n16 = lane & 15, q4 = lane >> 4;
#pragma unroll
    for (int tt = 0; tt < 4; ++tt) {
        u32 hb[4], lb[4];
#pragma unroll
        for (int r = 0; r < 4; ++r) {
            float v = acc[tt][r];
            hb[r] = bf16_rne(v);
            lb[r] = bf16_rne(v - bflo(hb[r]));
        }
        int off = (16 * tt + n16) * SROW + CB + 16 * wv + 4 * q4;
        *(uint2*)(Xhi + off) = make_uint2(hb[0] | (hb[1] << 16), hb[2] | (hb[3] << 16));
        *(uint2*)(Xlo + off) = make_uint2(lb[0] | (lb[1] << 16), lb[2] | (lb[3] << 16));
    }
}

// Stage agg = (S - msgs)/63 into X cols [CB, CB+64), hi+lo planes.
template <int SROW, int CB>
__device__ __forceinline__ void stage_agg(const u32* __restrict__ ms,
                                          const float* __restrict__ Ss,
                                          u16* Xhi, u16* Xlo, int t) {
    constexpr float inv63 = 1.0f / 63.0f;
#pragma unroll
    for (int q = 0; q < 4; ++q) {
        int grp = q * 256 + t;
        int u = grp >> 4, c4 = (grp & 15) * 4;
        uint2 mw = *(const uint2*)(ms + u * 32 + (c4 >> 1));
        float4 sv = *(const float4*)(Ss + u * 64 + c4);
        float a0 = (sv.x - bflo(mw.x)) * inv63;
        float a1 = (sv.y - bfhi(mw.x)) * inv63;
        float a2 = (sv.z - bflo(mw.y)) * inv63;
        float a3 = (sv.w - bfhi(mw.y)) * inv63;
        u32 h0 = bf16_rne(a0), h1 = bf16_rne(a1), h2 = bf16_rne(a2), h3 = bf16_rne(a3);
        u32 l0 = bf16_rne(a0 - bflo(h0));
        u32 l1 = bf16_rne(a1 - bflo(h1));
        u32 l2 = bf16_rne(a2 - bflo(h2));
        u32 l3 = bf16_rne(a3 - bflo(h3));
        int off = u * SROW + CB + c4;
        *(uint2*)(Xhi + off) = make_uint2(h0 | (h1 << 16), h2 | (h3 << 16));
        *(uint2*)(Xlo + off) = make_uint2(l0 | (l1 << 16), l2 | (l3 << 16));
    }
}

// -------------------------------------------------------------- reduce ----
// S[b][u][c] (fp32) = sum_a msgs[b,a][u][c] (bf16). Thread = one u32 (2 c's).
__global__ __launch_bounds__(256) void reduce_kernel(
    const u32* __restrict__ msgs, float* __restrict__ S)
{
    int idx = blockIdx.x * 256 + threadIdx.x;   // b*2048 + j
    int b = idx >> 11;
    int j = idx & 2047;
    const u32* p = msgs + (size_t)b * 131072 + j;
    float s0 = 0.0f, s1 = 0.0f;
#pragma unroll 8
    for (int a = 0; a < 64; ++a) {
        u32 w = p[(size_t)a * 2048];
        s0 += bflo(w);
        s1 += bfhi(w);
    }
    *(float2*)(S + (size_t)b * 4096 + 2 * j) = make_float2(s0, s1);
}

// ------------------------------------------------------------ phi1 ----
// First phi: L1 = rank-1 (cg,cg) only; L2 MFMA; writes bf16 msgs.
__global__ __launch_bounds__(256) void phi1_kernel(
    const float* __restrict__ cgT,
    const float* __restrict__ w0, const float* __restrict__ b1,
    const u16* __restrict__ A2, const float* __restrict__ b2,
    u16* __restrict__ mOut)
{
    constexpr int SROW = 72;
    __shared__ __align__(16) u16 Xhi[64 * SROW];
    __shared__ __align__(16) u16 Xlo[64 * SROW];
    const int t = threadIdx.x;
    const u32 sb = blockIdx.x;
    const int lane = t & 63;
    const int wv = t >> 6;
    const int n16 = lane & 15, q4 = lane >> 4;

    f32x4 acc[4];
    {
        const float4 bv = *(const float4*)(b1 + 16 * wv + 4 * q4);
        const float4 w0v = *(const float4*)(w0 + 16 * wv + 4 * q4);
#pragma unroll
        for (int tt = 0; tt < 4; ++tt) {
            float cgv = cgT[(size_t)sb * 64 + 16 * tt + n16];
            acc[tt][0] = bv.x + w0v.x * cgv; acc[tt][1] = bv.y + w0v.y * cgv;
            acc[tt][2] = bv.z + w0v.z * cgv; acc[tt][3] = bv.w + w0v.w * cgv;
        }
    }
#pragma unroll
    for (int tt = 0; tt < 4; ++tt)
#pragma unroll
        for (int r = 0; r < 4; ++r) acc[tt][r] = fmaxf(acc[tt][r], 0.0f);
    post_users_regs(acc, wv);
    stage_h<SROW, 0>(acc, Xhi, Xlo, lane, wv);
    __syncthreads();

    f32x4 acc2[4];
    {
        const float4 bv = *(const float4*)(b2 + 16 * wv + 4 * q4);
#pragma unroll
        for (int tt = 0; tt < 4; ++tt) { acc2[tt][0] = bv.x; acc2[tt][1] = bv.y; acc2[tt][2] = bv.z; acc2[tt][3] = bv.w; }
    }
    mfma_layer<2, SROW, true, 0>(A2, Xhi, Xlo, lane, wv, acc2);
    post_users_regs(acc2, wv);            // no relu (phi L2)

    __syncthreads();
#pragma unroll
    for (int tt = 0; tt < 4; ++tt) {
        u32 hb[4];
#pragma unroll
        for (int r = 0; r < 4; ++r) hb[r] = bf16_rne(acc2[tt][r]);
        int off = (16 * tt + n16) * 72 + 16 * wv + 4 * q4;
        *(uint2*)(Xhi + off) = make_uint2(hb[0] | (hb[1] << 16), hb[2] | (hb[3] << 16));
    }
    __syncthreads();
    u16* oM = mOut + (size_t)sb * 4096;
#pragma unroll
    for (int q = 0; q < 2; ++q) {
        int grp = q * 256 + t;
        int u = grp >> 3, c8 = (grp & 7) * 8;
        *(uint4*)(oM + u * 64 + c8) = *(const uint4*)(Xhi + u * 72 + c8);
    }
}

// ------------------------------------------------------------ fused ----
// F = [gamma_k ; phi_{k+1}] per (b,a) slab.
// KG = gamma L1 K (64 for gamma1 [cg|agg] with rank-1 cg; 128 for [r|agg]).
// Writes r_k (hi/lo planes) and msgs_{k+1} (bf16).
template <int KG>
__global__ __launch_bounds__(256) void fused_kernel(
    const float* __restrict__ cgT,
    const u16* __restrict__ rInHi, const u16* __restrict__ rInLo,
    const u32* __restrict__ mIn, const float* __restrict__ Sin,
    const u16* __restrict__ A1g, const float* __restrict__ w0g,
    const float* __restrict__ b1g,
    const u16* __restrict__ A2g, const float* __restrict__ b2g,
    const u16* __restrict__ A1p, const float* __restrict__ w0p,
    const float* __restrict__ b1p,
    const u16* __restrict__ A2p, const float* __restrict__ b2p,
    u16* __restrict__ rOutHi, u16* __restrict__ rOutLo, u16* __restrict__ mOut)
{
    constexpr int SROW = 136;
    __shared__ __align__(16) u16 Xhi[64 * SROW];
    __shared__ __align__(16) u16 Xlo[64 * SROW];
    const int t = threadIdx.x;
    const u32 sb = blockIdx.x;          // slab = (b_local, a)
    const u32 bloc = sb >> 6;
    const int lane = t & 63;
    const int wv = t >> 6;
    const int n16 = lane & 15, q4 = lane >> 4;

    // ---- stage gamma inputs: r (KG==128) at cols 0..63, agg at KG-64 ----
    if constexpr (KG == 128) {
        const u16* rsH = rInHi + (size_t)sb * 4096;
        const u16* rsL = rInLo + (size_t)sb * 4096;
#pragma unroll
        for (int q = 0; q < 2; ++q) {
            int grp = q * 256 + t;
            int u = grp >> 3, c8 = (grp & 7) * 8;
            *(uint4*)(Xhi + u * SROW + c8) = *(const uint4*)(rsH + u * 64 + c8);
            *(uint4*)(Xlo + u * SROW + c8) = *(const uint4*)(rsL + u * 64 + c8);
        }
    }
    stage_agg<SROW, KG - 64>(mIn + (size_t)sb * 2048, Sin + (size_t)bloc * 4096,
                             Xhi, Xlo, t);
    __syncthreads();

    // ---- gamma layer 1 ----
    f32x4 acc[4];
    {
        const float4 bv = *(const float4*)(b1g + 16 * wv + 4 * q4);
#pragma unroll
        for (int tt = 0; tt < 4; ++tt) { acc[tt][0] = bv.x; acc[tt][1] = bv.y; acc[tt][2] = bv.z; acc[tt][3] = bv.w; }
    }
    if constexpr (KG == 64) {           // gamma1: feats = cg (rank-1)
        const float4 w0v = *(const float4*)(w0g + 16 * wv + 4 * q4);
#pragma unroll
        for (int tt = 0; tt < 4; ++tt) {
            float cgv = cgT[(size_t)sb * 64 + 16 * tt + n16];
            acc[tt][0] += w0v.x * cgv; acc[tt][1] += w0v.y * cgv;
            acc[tt][2] += w0v.z * cgv; acc[tt][3] += w0v.w * cgv;
        }
    }
    mfma_layer<KG / 32, SROW, true, 0>(A1g, Xhi, Xlo, lane, wv, acc);
#pragma unroll
    for (int tt = 0; tt < 4; ++tt)
#pragma unroll
        for (int r = 0; r < 4; ++r) acc[tt][r] = fmaxf(acc[tt][r], 0.0f);
    post_users_regs(acc, wv);
    __syncthreads();
    stage_h<SROW, 0>(acc, Xhi, Xlo, lane, wv);
    __syncthreads();

    // ---- gamma layer 2 -> r_k ----
    f32x4 acc2[4];
    {
        const float4 bv = *(const float4*)(b2g + 16 * wv + 4 * q4);
#pragma unroll
        for (int tt = 0; tt < 4; ++tt) { acc2[tt][0] = bv.x; acc2[tt][1] = bv.y; acc2[tt][2] = bv.z; acc2[tt][3] = bv.w; }
    }
    mfma_layer<2, SROW, true, 0>(A2g, Xhi, Xlo, lane, wv, acc2);
#pragma unroll
    for (int tt = 0; tt < 4; ++tt)
#pragma unroll
        for (int r = 0; r < 4; ++r) acc2[tt][r] = fmaxf(acc2[tt][r], 0.0f);
    post_users_regs(acc2, wv);

    // ---- stage r_k into LDS cols 0..63; write r_k to HBM ----
    __syncthreads();
    stage_h<SROW, 0>(acc2, Xhi, Xlo, lane, wv);
    __syncthreads();
    {
        u16* oH = rOutHi + (size_t)sb * 4096;
        u16* oL = rOutLo + (size_t)sb * 4096;
#pragma unroll
        for (int q = 0; q < 2; ++q) {
            int grp = q * 256 + t;
            int u = grp >> 3, c8 = (grp & 7) * 8;
            *(uint4*)(oH + u * 64 + c8) = *(const uint4*)(Xhi + u * SROW + c8);
            *(uint4*)(oL + u * 64 + c8) = *(const uint4*)(Xlo + u * SROW + c8);
        }
    }

    // ---- phi layer 1: rank-1 cg + MFMA over r_k (LDS, hi+lo) ----
    f32x4 acc3[4];
    {
        const float4 bv = *(const float4*)(b1p + 16 * wv + 4 * q4);
        const float4 w0v = *(const float4*)(w0p + 16 * wv + 4 * q4);
#pragma unroll
        for (int tt = 0; tt < 4; ++tt) {
            float cgv = cgT[(size_t)sb * 64 + 16 * tt + n16];
            acc3[tt][0] = bv.x + w0v.x * cgv; acc3[tt][1] = bv.y + w0v.y * cgv;
            acc3[tt][2] = bv.z + w0v.z * cgv; acc3[tt][3] = bv.w + w0v.w * cgv;
        }
    }
    mfma_layer<2, SROW, true, 0>(A1p, Xhi, Xlo, lane, wv, acc3);
#pragma unroll
    for (int tt = 0; tt < 4; ++tt)
#pragma unroll
        for (int r = 0; r < 4; ++r) acc3[tt][r] = fmaxf(acc3[tt][r], 0.0f);
    post_users_regs(acc3, wv);
    __syncthreads();
    stage_h<SROW, 64>(acc3, Xhi, Xlo, lane, wv);   // h2 at cols 64..127
    __syncthreads();

    // ---- phi layer 2 -> msgs_{k+1} ----
    f32x4 acc4[4];
    {
        const float4 bv = *(const float4*)(b2p + 16 * wv + 4 * q4);
#pragma unroll
        for (int tt = 0; tt < 4; ++tt) { acc4[tt][0] = bv.x; acc4[tt][1] = bv.y; acc4[tt][2] = bv.z; acc4[tt][3] = bv.w; }
    }
    mfma_layer<2, SROW, true, 64>(A2p, Xhi, Xlo, lane, wv, acc4);
    post_users_regs(acc4, wv);            // no relu (phi L2)

    __syncthreads();
#pragma unroll
    for (int tt = 0; tt < 4; ++tt) {
        u32 hb[4];
#pragma unroll
        for (int r = 0; r < 4; ++r) hb[r] = bf16_rne(acc4[tt][r]);
        int off = (16 * tt + n16) * 72 + 16 * wv + 4 * q4;
        *(uint2*)(Xhi + off) = make_uint2(hb[0] | (hb[1] << 16), hb[2] | (hb[3] << 16));
    }
    __syncthreads();
    u16* oM = mOut + (size_t)sb * 4096;
#pragma unroll
    for (int q = 0; q < 2; ++q) {
        int grp = q * 256 + t;
        int u = grp >> 3, c8 = (grp & 7) * 8;
        *(uint4*)(oM + u * 64 + c8) = *(const uint4*)(Xhi + u * 72 + c8);
    }
}

// ------------------------------------------------------------ gamma5 ----
// Final gamma: [r | agg] K=128 L1; L2 = 1-row dot; writes fp32 out.
__global__ __launch_bounds__(256) void final_kernel(
    const u16* __restrict__ rInHi, const u16* __restrict__ rInLo,
    const u32* __restrict__ mIn, const float* __restrict__ Sin,
    const u16* __restrict__ A1, const float* __restrict__ b1,
    const float* __restrict__ w2raw, const float* __restrict__ b2raw,
    float* __restrict__ outF)
{
    constexpr int SROW = 136;
    __shared__ __align__(16) u16 Xhi[64 * SROW];
    __shared__ __align__(16) u16 Xlo[64 * SROW];
    __shared__ float part[4][64];
    const int t = threadIdx.x;
    const u32 sb = blockIdx.x;
    const u32 bloc = sb >> 6;
    const int lane = t & 63;
    const int wv = t >> 6;
    const int n16 = lane & 15, q4 = lane >> 4;

    {
        const u16* rsH = rInHi + (size_t)sb * 4096;
        const u16* rsL = rInLo + (size_t)sb * 4096;
#pragma unroll
        for (int q = 0; q < 2; ++q) {
            int grp = q * 256 + t;
            int u = grp >> 3, c8 = (grp & 7) * 8;
            *(uint4*)(Xhi + u * SROW + c8) = *(const uint4*)(rsH + u * 64 + c8);
            *(uint4*)(Xlo + u * SROW + c8) = *(const uint4*)(rsL + u * 64 + c8);
        }
    }
    stage_agg<SROW, 64>(mIn + (size_t)sb * 2048, Sin + (size_t)bloc * 4096,
                        Xhi, Xlo, t);
    __syncthreads();

    f32x4 acc[4];
    {
        const float4 bv = *(const float4*)(b1 + 16 * wv + 4 * q4);
#pragma unroll
        for (int tt = 0; tt < 4; ++tt) { acc[tt][0] = bv.x; acc[tt][1] = bv.y; acc[tt][2] = bv.z; acc[tt][3] = bv.w; }
    }
    mfma_layer<4, SROW, true, 0>(A1, Xhi, Xlo, lane, wv, acc);
#pragma unroll
    for (int tt = 0; tt < 4; ++tt)
#pragma unroll
        for (int r = 0; r < 4; ++r) acc[tt][r] = fmaxf(acc[tt][r], 0.0f);
    post_users_regs(acc, wv);
    __syncthreads();
    stage_h<SROW, 0>(acc, Xhi, Xlo, lane, wv);
    __syncthreads();

    const int cb2 = 16 * wv;
    const u16* hr = Xhi + lane * SROW + cb2;
    const u16* lr = Xlo + lane * SROW + cb2;
    bf16x8 h0 = *(const bf16x8*)hr;
    bf16x8 h1 = *(const bf16x8*)(hr + 8);
    bf16x8 l0 = *(const bf16x8*)lr;
    bf16x8 l1 = *(const bf16x8*)(lr + 8);
    float sum = 0.0f;
#pragma unroll
    for (int j = 0; j < 8; ++j) {
        float v0 = bflo((u32)(u16)h0[j]) + bflo((u32)(u16)l0[j]);
        float v1 = bflo((u32)(u16)h1[j]) + bflo((u32)(u16)l1[j]);
        sum += w2raw[cb2 + j] * v0;
        sum += w2raw[cb2 + 8 + j] * v1;
    }
    part[wv][lane] = sum;
    __syncthreads();
    if (t < 64) {
        float o = b2raw[0] + part[0][t] + part[1][t] + part[2][t] + part[3][t];
        outF[((size_t)bloc * 64 + t) * 64 + (sb & 63)] = o;
    }
}

// -------------------------------------------------------------- launch ----
extern "C" void kernel_launch(void* const* d_in, const int* in_sizes, int n_in,
                              void* d_out, int out_size, void* d_ws, size_t ws_size,
                              hipStream_t stream) {
    const float* cg      = (const float*)d_in[0];
    const float* phi1_W1 = (const float*)d_in[1];
    const float* phi1_b1 = (const float*)d_in[2];
    const float* phi1_W2 = (const float*)d_in[3];
    const float* phi1_b2 = (const float*)d_in[4];
    const float* phiK_W1 = (const float*)d_in[5];
    const float* phiK_b1 = (const float*)d_in[6];
    const float* phiK_W2 = (const float*)d_in[7];
    const float* phiK_b2 = (const float*)d_in[8];
    const float* g1_W1   = (const float*)d_in[9];
    const float* g1_b1   = (const float*)d_in[10];
    const float* g1_W2   = (const float*)d_in[11];
    const float* g1_b2   = (const float*)d_in[12];
    const float* gK_W1   = (const float*)d_in[13];
    const float* gK_b1   = (const float*)d_in[14];
    const float* gK_W2   = (const float*)d_in[15];
    const float* gK_b2   = (const float*)d_in[16];
    const float* g5_W1   = (const float*)d_in[17];
    const float* g5_b1   = (const float*)d_in[18];
    const float* g5_W2   = (const float*)d_in[19];
    const float* g5_b2   = (const float*)d_in[20];
    (void)in_sizes; (void)n_in; (void)out_size;

    // Footprint (bytes): rHi/rLo/msgs = 3*BC*524288, S = BC*16384,
    // cgT = 2 MB, Apack = 360448, w0s tiny.
    int BC = 128;
    while (BC > 4 && (size_t)BC * 1589248 + 2461696 > ws_size) BC >>= 1;
    const int NC = 128 / BC;

    u16*   rHi  = (u16*)d_ws;
    u16*   rLo  = rHi + (size_t)BC * 262144;
    u16*   msgs = rLo + (size_t)BC * 262144;
    float* S    = (float*)(msgs + (size_t)BC * 262144);
    float* cgT  = S + (size_t)BC * 4096;
    u16*   Apack = (u16*)(cgT + 524288);
    float* w0s  = (float*)(Apack + 180224);
    float* out  = (float*)d_out;

    prep_kernel<<<354 + 2048, 256, 0, stream>>>(cg, cgT, Apack, w0s,
        phi1_W1, phi1_W2, phiK_W1, phiK_W2, g1_W1, g1_W2, gK_W1, gK_W2, g5_W1);

    const int nblk = BC * 64;
    const int rblk = BC * 8;

    for (int c = 0; c < NC; ++c) {
        const float* cgTc = cgT + (size_t)c * BC * 4096;
        float* outc = out + (size_t)c * BC * 4096;

        // phi1 -> msgs
        phi1_kernel<<<nblk, 256, 0, stream>>>(cgTc, w0s, phi1_b1,
            Apack + 0, phi1_b2, msgs);
        reduce_kernel<<<rblk, 256, 0, stream>>>((const u32*)msgs, S);

        // [gamma1 + phiK0] -> r, msgs
        fused_kernel<64><<<nblk, 256, 0, stream>>>(cgTc, nullptr, nullptr,
            (const u32*)msgs, S,
            Apack + 73728, w0s + 320, g1_b1, Apack + 81920, g1_b2,
            Apack + 8192, w0s + 64, phiK_b1, Apack + 40960, phiK_b2,
            rHi, rLo, msgs);
        reduce_kernel<<<rblk, 256, 0, stream>>>((const u32*)msgs, S);

        // [gammaK[j] + phiK[j+1]] for j = 0..2
        for (int j = 0; j < 3; ++j) {
            fused_kernel<128><<<nblk, 256, 0, stream>>>(cgTc, rHi, rLo,
                (const u32*)msgs, S,
                Apack + 90112 + (size_t)j * 16384, nullptr, gK_b1 + j * 64,
                Apack + 139264 + (size_t)j * 8192, gK_b2 + j * 64,
                Apack + 8192 + (size_t)(j + 1) * 8192, w0s + 64 + (j + 1) * 64,
                phiK_b1 + (j + 1) * 64,
                Apack + 40960 + (size_t)(j + 1) * 8192, phiK_b2 + (j + 1) * 64,
                rHi, rLo, msgs);
            reduce_kernel<<<rblk, 256, 0, stream>>>((const u32*)msgs, S);
        }

        // gamma5 -> out
        final_kernel<<<nblk, 256, 0, stream>>>(rHi, rLo, (const u32*)msgs, S,
            Apack + 163840, g5_b1, g5_W2, g5_b2, outc);
    }
}

// Round 6
// 638.167 us; speedup vs baseline: 4.2847x; 1.1110x over previous
//
#include <hip/hip_runtime.h>

// GNN_19971597927185 — MFMA bf16 hi/lo-split, fused [gamma_k + phi_{k+1}].
// B=128, U=64, A=64. One workgroup (4 waves) per (b,a) fiber; wave wv owns
// output rows [16wv,16wv+16), 4 col-tiles over u.
// Storage: msgs = bf16 [u][c]; r = two bf16 planes (hi, lo) [u][c];
// S[b][u][c] fp32 via separate reduce kernel (no atomics).
// Round 6: phi-path B-operands hi-only (attenuated by /63 aggregation),
// v_cvt_pk_bf16_f32 packing, DPP row-16 reductions (off the LDS pipe).

typedef __attribute__((ext_vector_type(8))) short bf16x8;
typedef __attribute__((ext_vector_type(4))) float f32x4;
typedef unsigned int u32;
typedef unsigned short u16;

__device__ __forceinline__ u32 bf16_rne(float x) {
    u32 u = __float_as_uint(x);
    return (u + 0x7fffu + ((u >> 16) & 1u)) >> 16;
}
__device__ __forceinline__ float bflo(u32 w) { return __uint_as_float(w << 16); }
__device__ __forceinline__ float bfhi(u32 w) { return __uint_as_float(w & 0xffff0000u); }

// Pack two f32 -> packed bf16x2 (a in low 16, b in high 16), RNE.
__device__ __forceinline__ u32 cvt2(float a, float b) {
#if __has_builtin(__builtin_amdgcn_cvt_pk_bf16_f32)
    auto p = __builtin_amdgcn_cvt_pk_bf16_f32(a, b);
    u32 w; __builtin_memcpy(&w, &p, 4);
    return w;
#else
    return bf16_rne(a) | (bf16_rne(b) << 16);
#endif
}

// DPP lane move within 16-lane row.
template <int CTRL>
__device__ __forceinline__ float dpp_mov(float v) {
    int x = __builtin_amdgcn_update_dpp(0, __float_as_int(v), CTRL, 0xF, 0xF, true);
    return __int_as_float(x);
}
// Sum across the 16-lane row (all lanes get the sum). VALU-only (no LDS pipe).
__device__ __forceinline__ float row16_sum(float s) {
    s += dpp_mov<0xB1>(s);    // quad_perm xor1
    s += dpp_mov<0x4E>(s);    // quad_perm xor2
    s += dpp_mov<0x141>(s);   // row_half_mirror (adds other quad in half)
    s += dpp_mov<0x140>(s);   // row_mirror (adds other half)
    return s;
}

// ---------------------------------------------------------------- prep ----
__global__ __launch_bounds__(256) void prep_kernel(
    const float* __restrict__ cg, float* __restrict__ cgT,
    u16* __restrict__ packs, float* __restrict__ w0s,
    const float* __restrict__ phi1_W1, const float* __restrict__ phi1_W2,
    const float* __restrict__ phiK_W1, const float* __restrict__ phiK_W2,
    const float* __restrict__ g1_W1,   const float* __restrict__ g1_W2,
    const float* __restrict__ gK_W1,   const float* __restrict__ gK_W2,
    const float* __restrict__ g5_W1)
{
    const int bid = blockIdx.x;
    const int t = threadIdx.x;
    if (bid < 352) {
        int tid = bid * 256 + t;          // 0..90111 weight elements
        int layer, rem, nch;
        if (tid < 57344) { layer = tid >> 12; rem = tid & 4095; nch = 2; }
        else { layer = 14 + ((tid - 57344) >> 13); rem = (tid - 57344) & 8191; nch = 4; }
        const float* src; int stride, colOff; size_t dstBase;
        switch (layer) {
            case 0:  src = phi1_W2;                      stride = 64;  colOff = 0; dstBase = 0; break;
            case 1: case 2: case 3: case 4: {
                int k = layer - 1; src = phiK_W1 + k * 4160; stride = 65; colOff = 1;
                dstBase = 8192 + (size_t)k * 8192; break; }
            case 5: case 6: case 7: case 8: {
                int k = layer - 5; src = phiK_W2 + k * 4096; stride = 64; colOff = 0;
                dstBase = 40960 + (size_t)k * 8192; break; }
            case 9:  src = g1_W1;                        stride = 65;  colOff = 1; dstBase = 73728; break;
            case 10: src = g1_W2;                        stride = 64;  colOff = 0; dstBase = 81920; break;
            case 11: case 12: case 13: {
                int k = layer - 11; src = gK_W2 + k * 4096; stride = 64; colOff = 0;
                dstBase = 139264 + (size_t)k * 8192; break; }
            case 14: case 15: case 16: {
                int k = layer - 14; src = gK_W1 + k * 8192; stride = 128; colOff = 0;
                dstBase = 90112 + (size_t)k * 16384; break; }
            default: src = g5_W1;                        stride = 128; colOff = 0; dstBase = 163840; break;
        }
        int j = rem & 7;
        int lane = (rem >> 3) & 63;
        int rc = rem >> 9;                 // rb*nch + ch
        int rb = rc / nch;
        int ch = rc - rb * nch;
        int o = 16 * rb + (lane & 15);
        int c = colOff + ch * 32 + (lane >> 4) * 8 + j;
        float wv = src[o * stride + c];
        u32 hb = bf16_rne(wv);
        u32 lb = bf16_rne(wv - bflo(hb));
        size_t base = dstBase + (size_t)rc * 1024 + lane * 8 + j;
        packs[base] = (u16)hb;
        packs[base + 512] = (u16)lb;
    } else if (bid < 354) {
        int i = (bid - 352) * 256 + t;
        if (i < 64)       w0s[i] = phi1_W1[i * 2] + phi1_W1[i * 2 + 1];
        else if (i < 320) { int k = (i - 64) >> 6; int o = (i - 64) & 63; w0s[i] = phiK_W1[k * 4160 + o * 65]; }
        else if (i < 384) { int o = i - 320; w0s[i] = g1_W1[o * 65]; }
    } else {
        int idx = (bid - 354) * 256 + t;   // (b, a, u)
        int b = idx >> 12;
        int u = idx & 63;
        cgT[idx] = cg[((b << 6) + u) * 64 + ((idx >> 6) & 63)];
    }
}

// -------------------------------------------------------- MFMA helpers ----
// LO: B has a lo plane (3-MFMA); CB: column offset of B in the X buffer.
template <int NCH, int SROW, bool LO, int CB>
__device__ __forceinline__ void mfma_layer(const u16* __restrict__ A,
                                           const u16* Xhi, const u16* Xlo,
                                           int lane, int wv, f32x4 acc[4]) {
    const int n16 = lane & 15, q4 = lane >> 4;
#pragma unroll
    for (int ch = 0; ch < NCH; ++ch) {
        bf16x8 Ah = *(const bf16x8*)(A + ((size_t)(wv * NCH + ch) * 2) * 512 + lane * 8);
        bf16x8 Al = *(const bf16x8*)(A + ((size_t)(wv * NCH + ch) * 2 + 1) * 512 + lane * 8);
#pragma unroll
        for (int tt = 0; tt < 4; ++tt) {
            int boff = (16 * tt + n16) * SROW + CB + ch * 32 + q4 * 8;
            bf16x8 Bh = *(const bf16x8*)(Xhi + boff);
            acc[tt] = __builtin_amdgcn_mfma_f32_16x16x32_bf16(Ah, Bh, acc[tt], 0, 0, 0);
            acc[tt] = __builtin_amdgcn_mfma_f32_16x16x32_bf16(Al, Bh, acc[tt], 0, 0, 0);
            if constexpr (LO) {
                bf16x8 Bl = *(const bf16x8*)(Xlo + boff);
                acc[tt] = __builtin_amdgcn_mfma_f32_16x16x32_bf16(Ah, Bl, acc[tt], 0, 0, 0);
            }
        }
    }
}

// post_users on C-layout accs: rowsum over u (4 tiles + 16-lane row via DPP).
__device__ __forceinline__ void post_users_regs(f32x4 acc[4], int wv) {
    constexpr float inv63 = 1.0f / 63.0f;
#pragma unroll
    for (int r = 0; r < 4; ++r) {
        float s = row16_sum(acc[0][r] + acc[1][r] + acc[2][r] + acc[3][r]);
        if (wv >= 2) {      // rows >= 32: aggregated half (wave-uniform branch)
#pragma unroll
            for (int tt = 0; tt < 4; ++tt) acc[tt][r] = (s - acc[tt][r]) * inv63;
        }
    }
}

template <int SROW, int CB, bool WITH_LO>
__device__ __forceinline__ void stage_h(const f32x4 acc[4], u16* Xhi,
                                        u16* Xlo, int lane, int wv) {
    const int n16 = lane & 15, q4 = lane >> 4;
#pragma unroll
    for (int tt = 0; tt < 4; ++tt) {
        float v0 = acc[tt][0], v1 = acc[tt][1], v2 = acc[tt][2], v3 = acc[tt][3];
        u32 h01 = cvt2(v0, v1), h23 = cvt2(v2, v3);
        int off = (16 * tt + n16) * SROW + CB + 16 * wv + 4 * q4;
        *(uint2*)(Xhi + off) = make_uint2(h01, h23);
        if constexpr (WITH_LO) {
            u32 l01 = cvt2(v0 - bflo(h01), v1 - bfhi(h01));
            u32 l23 = cvt2(v2 - bflo(h23), v3 - bfhi(h23));
            *(uint2*)(Xlo + off) = make_uint2(l01, l23);
        }
    }
}

// Stage agg = (S - msgs)/63 into X cols [CB, CB+64), hi+lo planes.
template <int SROW, int CB>
__device__ __forceinline__ void stage_agg(const u32* __restrict__ ms,
                                          const float* __restrict__ Ss,
                                          u16* Xhi, u16* Xlo, int t) {
    constexpr float inv63 = 1.0f / 63.0f;
#pragma unroll
    for (int q = 0; q < 4; ++q) {
        int grp = q * 256 + t;
        int u = grp >> 4, c4 = (grp & 15) * 4;
        uint2 mw = *(const uint2*)(ms + u * 32 + (c4 >> 1));
        float4 sv = *(const float4*)(Ss + u * 64 + c4);
        float a0 = (sv.x - bflo(mw.x)) * inv63;
        float a1 = (sv.y - bfhi(mw.x)) * inv63;
        float a2 = (sv.z - bflo(mw.y)) * inv63;
        float a3 = (sv.w - bfhi(mw.y)) * inv63;
        u32 h01 = cvt2(a0, a1), h23 = cvt2(a2, a3);
        u32 l01 = cvt2(a0 - bflo(h01), a1 - bfhi(h01));
        u32 l23 = cvt2(a2 - bflo(h23), a3 - bfhi(h23));
        int off = u * SROW + CB + c4;
        *(uint2*)(Xhi + off) = make_uint2(h01, h23);
        *(uint2*)(Xlo + off) = make_uint2(l01, l23);
    }
}

// -------------------------------------------------------------- reduce ----
// S[b][u][c] (fp32) = sum_a msgs[b,a][u][c] (bf16). Thread = one u32 (2 c's).
__global__ __launch_bounds__(256) void reduce_kernel(
    const u32* __restrict__ msgs, float* __restrict__ S)
{
    int idx = blockIdx.x * 256 + threadIdx.x;   // b*2048 + j
    int b = idx >> 11;
    int j = idx & 2047;
    const u32* p = msgs + (size_t)b * 131072 + j;
    float s0 = 0.0f, s1 = 0.0f;
#pragma unroll 8
    for (int a = 0; a < 64; ++a) {
        u32 w = p[(size_t)a * 2048];
        s0 += bflo(w);
        s1 += bfhi(w);
    }
    *(float2*)(S + (size_t)b * 4096 + 2 * j) = make_float2(s0, s1);
}

// ------------------------------------------------------------ phi1 ----
// First phi: L1 = rank-1 (cg,cg) only; L2 MFMA (h hi-only); writes bf16 msgs.
__global__ __launch_bounds__(256) void phi1_kernel(
    const float* __restrict__ cgT,
    const float* __restrict__ w0, const float* __restrict__ b1,
    const u16* __restrict__ A2, const float* __restrict__ b2,
    u16* __restrict__ mOut)
{
    constexpr int SROW = 72;
    __shared__ __align__(16) u16 Xhi[64 * SROW];
    const int t = threadIdx.x;
    const u32 sb = blockIdx.x;
    const int lane = t & 63;
    const int wv = t >> 6;
    const int n16 = lane & 15, q4 = lane >> 4;

    f32x4 acc[4];
    {
        const float4 bv = *(const float4*)(b1 + 16 * wv + 4 * q4);
        const float4 w0v = *(const float4*)(w0 + 16 * wv + 4 * q4);
#pragma unroll
        for (int tt = 0; tt < 4; ++tt) {
            float cgv = cgT[(size_t)sb * 64 + 16 * tt + n16];
            acc[tt][0] = bv.x + w0v.x * cgv; acc[tt][1] = bv.y + w0v.y * cgv;
            acc[tt][2] = bv.z + w0v.z * cgv; acc[tt][3] = bv.w + w0v.w * cgv;
        }
    }
#pragma unroll
    for (int tt = 0; tt < 4; ++tt)
#pragma unroll
        for (int r = 0; r < 4; ++r) acc[tt][r] = fmaxf(acc[tt][r], 0.0f);
    post_users_regs(acc, wv);
    stage_h<SROW, 0, false>(acc, Xhi, nullptr, lane, wv);
    __syncthreads();

    f32x4 acc2[4];
    {
        const float4 bv = *(const float4*)(b2 + 16 * wv + 4 * q4);
#pragma unroll
        for (int tt = 0; tt < 4; ++tt) { acc2[tt][0] = bv.x; acc2[tt][1] = bv.y; acc2[tt][2] = bv.z; acc2[tt][3] = bv.w; }
    }
    mfma_layer<2, SROW, false, 0>(A2, Xhi, nullptr, lane, wv, acc2);
    post_users_regs(acc2, wv);            // no relu (phi L2)

    __syncthreads();
#pragma unroll
    for (int tt = 0; tt < 4; ++tt) {
        u32 h01 = cvt2(acc2[tt][0], acc2[tt][1]);
        u32 h23 = cvt2(acc2[tt][2], acc2[tt][3]);
        int off = (16 * tt + n16) * 72 + 16 * wv + 4 * q4;
        *(uint2*)(Xhi + off) = make_uint2(h01, h23);
    }
    __syncthreads();
    u16* oM = mOut + (size_t)sb * 4096;
#pragma unroll
    for (int q = 0; q < 2; ++q) {
        int grp = q * 256 + t;
        int u = grp >> 3, c8 = (grp & 7) * 8;
        *(uint4*)(oM + u * 64 + c8) = *(const uint4*)(Xhi + u * 72 + c8);
    }
}

// ------------------------------------------------------------ fused ----
// [gamma_k ; phi_{k+1}] per (b,a) slab.
// KG = gamma L1 K (64 for gamma1 [cg|agg] with rank-1 cg; 128 for [r|agg]).
// Writes r_k (hi/lo planes) and msgs_{k+1} (bf16).
template <int KG>
__global__ __launch_bounds__(256) void fused_kernel(
    const float* __restrict__ cgT,
    const u16* __restrict__ rInHi, const u16* __restrict__ rInLo,
    const u32* __restrict__ mIn, const float* __restrict__ Sin,
    const u16* __restrict__ A1g, const float* __restrict__ w0g,
    const float* __restrict__ b1g,
    const u16* __restrict__ A2g, const float* __restrict__ b2g,
    const u16* __restrict__ A1p, const float* __restrict__ w0p,
    const float* __restrict__ b1p,
    const u16* __restrict__ A2p, const float* __restrict__ b2p,
    u16* __restrict__ rOutHi, u16* __restrict__ rOutLo, u16* __restrict__ mOut)
{
    constexpr int SROW = 136;
    __shared__ __align__(16) u16 Xhi[64 * SROW];
    __shared__ __align__(16) u16 Xlo[64 * SROW];
    const int t = threadIdx.x;
    const u32 sb = blockIdx.x;          // slab = (b_local, a)
    const u32 bloc = sb >> 6;
    const int lane = t & 63;
    const int wv = t >> 6;
    const int n16 = lane & 15, q4 = lane >> 4;

    // ---- stage gamma inputs: r (KG==128) at cols 0..63, agg at KG-64 ----
    if constexpr (KG == 128) {
        const u16* rsH = rInHi + (size_t)sb * 4096;
        const u16* rsL = rInLo + (size_t)sb * 4096;
#pragma unroll
        for (int q = 0; q < 2; ++q) {
            int grp = q * 256 + t;
            int u = grp >> 3, c8 = (grp & 7) * 8;
            *(uint4*)(Xhi + u * SROW + c8) = *(const uint4*)(rsH + u * 64 + c8);
            *(uint4*)(Xlo + u * SROW + c8) = *(const uint4*)(rsL + u * 64 + c8);
        }
    }
    stage_agg<SROW, KG - 64>(mIn + (size_t)sb * 2048, Sin + (size_t)bloc * 4096,
                             Xhi, Xlo, t);
    __syncthreads();

    // ---- gamma layer 1 ----
    f32x4 acc[4];
    {
        const float4 bv = *(const float4*)(b1g + 16 * wv + 4 * q4);
#pragma unroll
        for (int tt = 0; tt < 4; ++tt) { acc[tt][0] = bv.x; acc[tt][1] = bv.y; acc[tt][2] = bv.z; acc[tt][3] = bv.w; }
    }
    if constexpr (KG == 64) {           // gamma1: feats = cg (rank-1)
        const float4 w0v = *(const float4*)(w0g + 16 * wv + 4 * q4);
#pragma unroll
        for (int tt = 0; tt < 4; ++tt) {
            float cgv = cgT[(size_t)sb * 64 + 16 * tt + n16];
            acc[tt][0] += w0v.x * cgv; acc[tt][1] += w0v.y * cgv;
            acc[tt][2] += w0v.z * cgv; acc[tt][3] += w0v.w * cgv;
        }
    }
    mfma_layer<KG / 32, SROW, true, 0>(A1g, Xhi, Xlo, lane, wv, acc);
#pragma unroll
    for (int tt = 0; tt < 4; ++tt)
#pragma unroll
        for (int r = 0; r < 4; ++r) acc[tt][r] = fmaxf(acc[tt][r], 0.0f);
    post_users_regs(acc, wv);
    __syncthreads();                     // L1 B-reads done before h overwrite
    stage_h<SROW, 0, true>(acc, Xhi, Xlo, lane, wv);
    __syncthreads();

    // ---- gamma layer 2 -> r_k ----
    f32x4 acc2[4];
    {
        const float4 bv = *(const float4*)(b2g + 16 * wv + 4 * q4);
#pragma unroll
        for (int tt = 0; tt < 4; ++tt) { acc2[tt][0] = bv.x; acc2[tt][1] = bv.y; acc2[tt][2] = bv.z; acc2[tt][3] = bv.w; }
    }
    mfma_layer<2, SROW, true, 0>(A2g, Xhi, Xlo, lane, wv, acc2);
#pragma unroll
    for (int tt = 0; tt < 4; ++tt)
#pragma unroll
        for (int r = 0; r < 4; ++r) acc2[tt][r] = fmaxf(acc2[tt][r], 0.0f);
    post_users_regs(acc2, wv);

    // ---- stage r_k into LDS cols 0..63; write r_k to HBM ----
    __syncthreads();                     // L2 B-reads done before r overwrite
    stage_h<SROW, 0, true>(acc2, Xhi, Xlo, lane, wv);
    __syncthreads();
    {
        u16* oH = rOutHi + (size_t)sb * 4096;
        u16* oL = rOutLo + (size_t)sb * 4096;
#pragma unroll
        for (int q = 0; q < 2; ++q) {
            int grp = q * 256 + t;
            int u = grp >> 3, c8 = (grp & 7) * 8;
            *(uint4*)(oH + u * 64 + c8) = *(const uint4*)(Xhi + u * SROW + c8);
            *(uint4*)(oL + u * 64 + c8) = *(const uint4*)(Xlo + u * SROW + c8);
        }
    }

    // ---- phi layer 1: rank-1 cg + MFMA over r_k (LDS, hi-only) ----
    f32x4 acc3[4];
    {
        const float4 bv = *(const float4*)(b1p + 16 * wv + 4 * q4);
        const float4 w0v = *(const float4*)(w0p + 16 * wv + 4 * q4);
#pragma unroll
        for (int tt = 0; tt < 4; ++tt) {
            float cgv = cgT[(size_t)sb * 64 + 16 * tt + n16];
            acc3[tt][0] = bv.x + w0v.x * cgv; acc3[tt][1] = bv.y + w0v.y * cgv;
            acc3[tt][2] = bv.z + w0v.z * cgv; acc3[tt][3] = bv.w + w0v.w * cgv;
        }
    }
    mfma_layer<2, SROW, false, 0>(A1p, Xhi, nullptr, lane, wv, acc3);
#pragma unroll
    for (int tt = 0; tt < 4; ++tt)
#pragma unroll
        for (int r = 0; r < 4; ++r) acc3[tt][r] = fmaxf(acc3[tt][r], 0.0f);
    post_users_regs(acc3, wv);
    // cols 64..127 have no live readers (gamma L1 finished 2 barriers ago)
    stage_h<SROW, 64, false>(acc3, Xhi, nullptr, lane, wv);
    __syncthreads();

    // ---- phi layer 2 -> msgs_{k+1} (h hi-only) ----
    f32x4 acc4[4];
    {
        const float4 bv = *(const float4*)(b2p + 16 * wv + 4 * q4);
#pragma unroll
        for (int tt = 0; tt < 4; ++tt) { acc4[tt][0] = bv.x; acc4[tt][1] = bv.y; acc4[tt][2] = bv.z; acc4[tt][3] = bv.w; }
    }
    mfma_layer<2, SROW, false, 64>(A2p, Xhi, nullptr, lane, wv, acc4);
    post_users_regs(acc4, wv);            // no relu (phi L2)

    __syncthreads();
#pragma unroll
    for (int tt = 0; tt < 4; ++tt) {
        u32 h01 = cvt2(acc4[tt][0], acc4[tt][1]);
        u32 h23 = cvt2(acc4[tt][2], acc4[tt][3]);
        int off = (16 * tt + n16) * 72 + 16 * wv + 4 * q4;
        *(uint2*)(Xhi + off) = make_uint2(h01, h23);
    }
    __syncthreads();
    u16* oM = mOut + (size_t)sb * 4096;
#pragma unroll
    for (int q = 0; q < 2; ++q) {
        int grp = q * 256 + t;
        int u = grp >> 3, c8 = (grp & 7) * 8;
        *(uint4*)(oM + u * 64 + c8) = *(const uint4*)(Xhi + u * 72 + c8);
    }
}

// ------------------------------------------------------------ gamma5 ----
// Final gamma: [r | agg] K=128 L1; L2 = 1-row dot; writes fp32 out.
__global__ __launch_bounds__(256) void final_kernel(
    const u16* __restrict__ rInHi, const u16* __restrict__ rInLo,
    const u32* __restrict__ mIn, const float* __restrict__ Sin,
    const u16* __restrict__ A1, const float* __restrict__ b1,
    const float* __restrict__ w2raw, const float* __restrict__ b2raw,
    float* __restrict__ outF)
{
    constexpr int SROW = 136;
    __shared__ __align__(16) u16 Xhi[64 * SROW];
    __shared__ __align__(16) u16 Xlo[64 * SROW];
    __shared__ float part[4][64];
    const int t = threadIdx.x;
    const u32 sb = blockIdx.x;
    const u32 bloc = sb >> 6;
    const int lane = t & 63;
    const int wv = t >> 6;
    const int n16 = lane & 15, q4 = lane >> 4;

    {
        const u16* rsH = rInHi + (size_t)sb * 4096;
        const u16* rsL = rInLo + (size_t)sb * 4096;
#pragma unroll
        for (int q = 0; q < 2; ++q) {
            int grp = q * 256 + t;
            int u = grp >> 3, c8 = (grp & 7) * 8;
            *(uint4*)(Xhi + u * SROW + c8) = *(const uint4*)(rsH + u * 64 + c8);
            *(uint4*)(Xlo + u * SROW + c8) = *(const uint4*)(rsL + u * 64 + c8);
        }
    }
    stage_agg<SROW, 64>(mIn + (size_t)sb * 2048, Sin + (size_t)bloc * 4096,
                        Xhi, Xlo, t);
    __syncthreads();

    f32x4 acc[4];
    {
        const float4 bv = *(const float4*)(b1 + 16 * wv + 4 * q4);
#pragma unroll
        for (int tt = 0; tt < 4; ++tt) { acc[tt][0] = bv.x; acc[tt][1] = bv.y; acc[tt][2] = bv.z; acc[tt][3] = bv.w; }
    }
    mfma_layer<4, SROW, true, 0>(A1, Xhi, Xlo, lane, wv, acc);
#pragma unroll
    for (int tt = 0; tt < 4; ++tt)
#pragma unroll
        for (int r = 0; r < 4; ++r) acc[tt][r] = fmaxf(acc[tt][r], 0.0f);
    post_users_regs(acc, wv);
    __syncthreads();
    stage_h<SROW, 0, true>(acc, Xhi, Xlo, lane, wv);
    __syncthreads();

    const int cb2 = 16 * wv;
    const u16* hr = Xhi + lane * SROW + cb2;
    const u16* lr = Xlo + lane * SROW + cb2;
    bf16x8 h0 = *(const bf16x8*)hr;
    bf16x8 h1 = *(const bf16x8*)(hr + 8);
    bf16x8 l0 = *(const bf16x8*)lr;
    bf16x8 l1 = *(const bf16x8*)(lr + 8);
    float sum = 0.0f;
#pragma unroll
    for (int j = 0; j < 8; ++j) {
        float v0 = bflo((u32)(u16)h0[j]) + bflo((u32)(u16)l0[j]);
        float v1 = bflo((u32)(u16)h1[j]) + bflo((u32)(u16)l1[j]);
        sum += w2raw[cb2 + j] * v0;
        sum += w2raw[cb2 + 8 + j] * v1;
    }
    part[wv][lane] = sum;
    __syncthreads();
    if (t < 64) {
        float o = b2raw[0] + part[0][t] + part[1][t] + part[2][t] + part[3][t];
        outF[((size_t)bloc * 64 + t) * 64 + (sb & 63)] = o;
    }
}

// -------------------------------------------------------------- launch ----
extern "C" void kernel_launch(void* const* d_in, const int* in_sizes, int n_in,
                              void* d_out, int out_size, void* d_ws, size_t ws_size,
                              hipStream_t stream) {
    const float* cg      = (const float*)d_in[0];
    const float* phi1_W1 = (const float*)d_in[1];
    const float* phi1_b1 = (const float*)d_in[2];
    const float* phi1_W2 = (const float*)d_in[3];
    const float* phi1_b2 = (const float*)d_in[4];
    const float* phiK_W1 = (const float*)d_in[5];
    const float* phiK_b1 = (const float*)d_in[6];
    const float* phiK_W2 = (const float*)d_in[7];
    const float* phiK_b2 = (const float*)d_in[8];
    const float* g1_W1   = (const float*)d_in[9];
    const float* g1_b1   = (const float*)d_in[10];
    const float* g1_W2   = (const float*)d_in[11];
    const float* g1_b2   = (const float*)d_in[12];
    const float* gK_W1   = (const float*)d_in[13];
    const float* gK_b1   = (const float*)d_in[14];
    const float* gK_W2   = (const float*)d_in[15];
    const float* gK_b2   = (const float*)d_in[16];
    const float* g5_W1   = (const float*)d_in[17];
    const float* g5_b1   = (const float*)d_in[18];
    const float* g5_W2   = (const float*)d_in[19];
    const float* g5_b2   = (const float*)d_in[20];
    (void)in_sizes; (void)n_in; (void)out_size;

    // Footprint (bytes): rHi/rLo/msgs = 3*BC*524288, S = BC*16384,
    // cgT = 2 MB, Apack = 360448, w0s tiny.
    int BC = 128;
    while (BC > 4 && (size_t)BC * 1589248 + 2461696 > ws_size) BC >>= 1;
    const int NC = 128 / BC;

    u16*   rHi  = (u16*)d_ws;
    u16*   rLo  = rHi + (size_t)BC * 262144;
    u16*   msgs = rLo + (size_t)BC * 262144;
    float* S    = (float*)(msgs + (size_t)BC * 262144);
    float* cgT  = S + (size_t)BC * 4096;
    u16*   Apack = (u16*)(cgT + 524288);
    float* w0s  = (float*)(Apack + 180224);
    float* out  = (float*)d_out;

    prep_kernel<<<354 + 2048, 256, 0, stream>>>(cg, cgT, Apack, w0s,
        phi1_W1, phi1_W2, phiK_W1, phiK_W2, g1_W1, g1_W2, gK_W1, gK_W2, g5_W1);

    const int nblk = BC * 64;
    const int rblk = BC * 8;

    for (int c = 0; c < NC; ++c) {
        const float* cgTc = cgT + (size_t)c * BC * 4096;
        float* outc = out + (size_t)c * BC * 4096;

        // phi1 -> msgs
        phi1_kernel<<<nblk, 256, 0, stream>>>(cgTc, w0s, phi1_b1,
            Apack + 0, phi1_b2, msgs);
        reduce_kernel<<<rblk, 256, 0, stream>>>((const u32*)msgs, S);

        // [gamma1 + phiK0] -> r, msgs
        fused_kernel<64><<<nblk, 256, 0, stream>>>(cgTc, nullptr, nullptr,
            (const u32*)msgs, S,
            Apack + 73728, w0s + 320, g1_b1, Apack + 81920, g1_b2,
            Apack + 8192, w0s + 64, phiK_b1, Apack + 40960, phiK_b2,
            rHi, rLo, msgs);
        reduce_kernel<<<rblk, 256, 0, stream>>>((const u32*)msgs, S);

        // [gammaK[j] + phiK[j+1]] for j = 0..2
        for (int j = 0; j < 3; ++j) {
            fused_kernel<128><<<nblk, 256, 0, stream>>>(cgTc, rHi, rLo,
                (const u32*)msgs, S,
                Apack + 90112 + (size_t)j * 16384, nullptr, gK_b1 + j * 64,
                Apack + 139264 + (size_t)j * 8192, gK_b2 + j * 64,
                Apack + 8192 + (size_t)(j + 1) * 8192, w0s + 64 + (j + 1) * 64,
                phiK_b1 + (j + 1) * 64,
                Apack + 40960 + (size_t)(j + 1) * 8192, phiK_b2 + (j + 1) * 64,
                rHi, rLo, msgs);
            reduce_kernel<<<rblk, 256, 0, stream>>>((const u32*)msgs, S);
        }

        // gamma5 -> out
        final_kernel<<<nblk, 256, 0, stream>>>(rHi, rLo, (const u32*)msgs, S,
            Apack + 163840, g5_b1, g5_W2, g5_b2, outc);
    }
}

// Round 7
// 615.568 us; speedup vs baseline: 4.4421x; 1.0367x over previous
//
#include <hip/hip_runtime.h>

// GNN_19971597927185 — MFMA bf16 hi/lo-split, fused [gamma_k + phi_{k+1}].
// B=128, U=64, A=64. One workgroup (4 waves) per (b,a) fiber; wave wv owns
// output rows [16wv,16wv+16), 4 col-tiles over u.
// Storage: msgs = bf16 [u][c]; r = two bf16 planes (hi, lo) [u][c];
// S[b][u][c] fp32 via separate reduce kernel (no atomics).
// Round 7: agg B-operand hi-only (drops lo staging+MFMAs), Xlo shrunk to
// 72 cols (LDS 34.8->26.6 KB: 6 blocks/CU), cg loads hoisted.

typedef __attribute__((ext_vector_type(8))) short bf16x8;
typedef __attribute__((ext_vector_type(4))) float f32x4;
typedef unsigned int u32;
typedef unsigned short u16;

#define SROWL 72   // Xlo row stride (u16) — lo plane only spans cols 0..63

__device__ __forceinline__ u32 bf16_rne(float x) {
    u32 u = __float_as_uint(x);
    return (u + 0x7fffu + ((u >> 16) & 1u)) >> 16;
}
__device__ __forceinline__ float bflo(u32 w) { return __uint_as_float(w << 16); }
__device__ __forceinline__ float bfhi(u32 w) { return __uint_as_float(w & 0xffff0000u); }

// Pack two f32 -> packed bf16x2 (a low 16, b high 16), RNE.
__device__ __forceinline__ u32 cvt2(float a, float b) {
#if __has_builtin(__builtin_amdgcn_cvt_pk_bf16_f32)
    auto p = __builtin_amdgcn_cvt_pk_bf16_f32(a, b);
    u32 w; __builtin_memcpy(&w, &p, 4);
    return w;
#else
    return bf16_rne(a) | (bf16_rne(b) << 16);
#endif
}

// DPP lane move within 16-lane row.
template <int CTRL>
__device__ __forceinline__ float dpp_mov(float v) {
    int x = __builtin_amdgcn_update_dpp(0, __float_as_int(v), CTRL, 0xF, 0xF, true);
    return __int_as_float(x);
}
// Sum across the 16-lane row (all lanes get the sum). VALU-only.
__device__ __forceinline__ float row16_sum(float s) {
    s += dpp_mov<0xB1>(s);    // quad_perm xor1
    s += dpp_mov<0x4E>(s);    // quad_perm xor2
    s += dpp_mov<0x141>(s);   // row_half_mirror
    s += dpp_mov<0x140>(s);   // row_mirror
    return s;
}

// ---------------------------------------------------------------- prep ----
__global__ __launch_bounds__(256) void prep_kernel(
    const float* __restrict__ cg, float* __restrict__ cgT,
    u16* __restrict__ packs, float* __restrict__ w0s,
    const float* __restrict__ phi1_W1, const float* __restrict__ phi1_W2,
    const float* __restrict__ phiK_W1, const float* __restrict__ phiK_W2,
    const float* __restrict__ g1_W1,   const float* __restrict__ g1_W2,
    const float* __restrict__ gK_W1,   const float* __restrict__ gK_W2,
    const float* __restrict__ g5_W1)
{
    const int bid = blockIdx.x;
    const int t = threadIdx.x;
    if (bid < 352) {
        int tid = bid * 256 + t;          // 0..90111 weight elements
        int layer, rem, nch;
        if (tid < 57344) { layer = tid >> 12; rem = tid & 4095; nch = 2; }
        else { layer = 14 + ((tid - 57344) >> 13); rem = (tid - 57344) & 8191; nch = 4; }
        const float* src; int stride, colOff; size_t dstBase;
        switch (layer) {
            case 0:  src = phi1_W2;                      stride = 64;  colOff = 0; dstBase = 0; break;
            case 1: case 2: case 3: case 4: {
                int k = layer - 1; src = phiK_W1 + k * 4160; stride = 65; colOff = 1;
                dstBase = 8192 + (size_t)k * 8192; break; }
            case 5: case 6: case 7: case 8: {
                int k = layer - 5; src = phiK_W2 + k * 4096; stride = 64; colOff = 0;
                dstBase = 40960 + (size_t)k * 8192; break; }
            case 9:  src = g1_W1;                        stride = 65;  colOff = 1; dstBase = 73728; break;
            case 10: src = g1_W2;                        stride = 64;  colOff = 0; dstBase = 81920; break;
            case 11: case 12: case 13: {
                int k = layer - 11; src = gK_W2 + k * 4096; stride = 64; colOff = 0;
                dstBase = 139264 + (size_t)k * 8192; break; }
            case 14: case 15: case 16: {
                int k = layer - 14; src = gK_W1 + k * 8192; stride = 128; colOff = 0;
                dstBase = 90112 + (size_t)k * 16384; break; }
            default: src = g5_W1;                        stride = 128; colOff = 0; dstBase = 163840; break;
        }
        int j = rem & 7;
        int lane = (rem >> 3) & 63;
        int rc = rem >> 9;                 // rb*nch + ch
        int rb = rc / nch;
        int ch = rc - rb * nch;
        int o = 16 * rb + (lane & 15);
        int c = colOff + ch * 32 + (lane >> 4) * 8 + j;
        float wv = src[o * stride + c];
        u32 hb = bf16_rne(wv);
        u32 lb = bf16_rne(wv - bflo(hb));
        size_t base = dstBase + (size_t)rc * 1024 + lane * 8 + j;
        packs[base] = (u16)hb;
        packs[base + 512] = (u16)lb;
    } else if (bid < 354) {
        int i = (bid - 352) * 256 + t;
        if (i < 64)       w0s[i] = phi1_W1[i * 2] + phi1_W1[i * 2 + 1];
        else if (i < 320) { int k = (i - 64) >> 6; int o = (i - 64) & 63; w0s[i] = phiK_W1[k * 4160 + o * 65]; }
        else if (i < 384) { int o = i - 320; w0s[i] = g1_W1[o * 65]; }
    } else {
        int idx = (bid - 354) * 256 + t;   // (b, a, u)
        int b = idx >> 12;
        int u = idx & 63;
        cgT[idx] = cg[((b << 6) + u) * 64 + ((idx >> 6) & 63)];
    }
}

// -------------------------------------------------------- MFMA helpers ----
// NLO: first NLO channels carry a lo plane (3-MFMA, Xlo @ stride SROWL);
// remaining channels hi-only (2-MFMA). CB: column offset in Xhi (lo only
// valid at CB==0).
template <int NCH, int NLO, int SROW, int CB>
__device__ __forceinline__ void mfma_layer(const u16* __restrict__ A,
                                           const u16* Xhi, const u16* Xlo,
                                           int lane, int wv, f32x4 acc[4]) {
    const int n16 = lane & 15, q4 = lane >> 4;
#pragma unroll
    for (int ch = 0; ch < NCH; ++ch) {
        bf16x8 Ah = *(const bf16x8*)(A + ((size_t)(wv * NCH + ch) * 2) * 512 + lane * 8);
        bf16x8 Al = *(const bf16x8*)(A + ((size_t)(wv * NCH + ch) * 2 + 1) * 512 + lane * 8);
#pragma unroll
        for (int tt = 0; tt < 4; ++tt) {
            int boff = (16 * tt + n16) * SROW + CB + ch * 32 + q4 * 8;
            bf16x8 Bh = *(const bf16x8*)(Xhi + boff);
            acc[tt] = __builtin_amdgcn_mfma_f32_16x16x32_bf16(Ah, Bh, acc[tt], 0, 0, 0);
            acc[tt] = __builtin_amdgcn_mfma_f32_16x16x32_bf16(Al, Bh, acc[tt], 0, 0, 0);
            if (ch < NLO) {
                int loff = (16 * tt + n16) * SROWL + ch * 32 + q4 * 8;
                bf16x8 Bl = *(const bf16x8*)(Xlo + loff);
                acc[tt] = __builtin_amdgcn_mfma_f32_16x16x32_bf16(Ah, Bl, acc[tt], 0, 0, 0);
            }
        }
    }
}

// post_users on C-layout accs: rowsum over u (4 tiles + 16-lane row via DPP).
__device__ __forceinline__ void post_users_regs(f32x4 acc[4], int wv) {
    constexpr float inv63 = 1.0f / 63.0f;
#pragma unroll
    for (int r = 0; r < 4; ++r) {
        float s = row16_sum(acc[0][r] + acc[1][r] + acc[2][r] + acc[3][r]);
        if (wv >= 2) {      // rows >= 32: aggregated half (wave-uniform branch)
#pragma unroll
            for (int tt = 0; tt < 4; ++tt) acc[tt][r] = (s - acc[tt][r]) * inv63;
        }
    }
}

// Stage C-layout acc into Xhi cols [CB,CB+64) (stride SROW); lo into Xlo
// (stride SROWL, cols 0..63 — only when CB==0).
template <int SROW, int CB, bool WITH_LO>
__device__ __forceinline__ void stage_h(const f32x4 acc[4], u16* Xhi,
                                        u16* Xlo, int lane, int wv) {
    const int n16 = lane & 15, q4 = lane >> 4;
#pragma unroll
    for (int tt = 0; tt < 4; ++tt) {
        float v0 = acc[tt][0], v1 = acc[tt][1], v2 = acc[tt][2], v3 = acc[tt][3];
        u32 h01 = cvt2(v0, v1), h23 = cvt2(v2, v3);
        int off = (16 * tt + n16) * SROW + CB + 16 * wv + 4 * q4;
        *(uint2*)(Xhi + off) = make_uint2(h01, h23);
        if constexpr (WITH_LO) {
            u32 l01 = cvt2(v0 - bflo(h01), v1 - bfhi(h01));
            u32 l23 = cvt2(v2 - bflo(h23), v3 - bfhi(h23));
            int loff = (16 * tt + n16) * SROWL + 16 * wv + 4 * q4;
            *(uint2*)(Xlo + loff) = make_uint2(l01, l23);
        }
    }
}

// Stage agg = (S - msgs)/63 into Xhi cols [CB, CB+64) — hi plane only.
template <int SROW, int CB>
__device__ __forceinline__ void stage_agg(const u32* __restrict__ ms,
                                          const float* __restrict__ Ss,
                                          u16* Xhi, int t) {
    constexpr float inv63 = 1.0f / 63.0f;
#pragma unroll
    for (int q = 0; q < 4; ++q) {
        int grp = q * 256 + t;
        int u = grp >> 4, c4 = (grp & 15) * 4;
        uint2 mw = *(const uint2*)(ms + u * 32 + (c4 >> 1));
        float4 sv = *(const float4*)(Ss + u * 64 + c4);
        float a0 = (sv.x - bflo(mw.x)) * inv63;
        float a1 = (sv.y - bfhi(mw.x)) * inv63;
        float a2 = (sv.z - bflo(mw.y)) * inv63;
        float a3 = (sv.w - bfhi(mw.y)) * inv63;
        int off = u * SROW + CB + c4;
        *(uint2*)(Xhi + off) = make_uint2(cvt2(a0, a1), cvt2(a2, a3));
    }
}

// -------------------------------------------------------------- reduce ----
// S[b][u][c] (fp32) = sum_a msgs[b,a][u][c] (bf16). Thread = one u32 (2 c's).
__global__ __launch_bounds__(256) void reduce_kernel(
    const u32* __restrict__ msgs, float* __restrict__ S)
{
    int idx = blockIdx.x * 256 + threadIdx.x;   // b*2048 + j
    int b = idx >> 11;
    int j = idx & 2047;
    const u32* p = msgs + (size_t)b * 131072 + j;
    float s0 = 0.0f, s1 = 0.0f;
#pragma unroll 8
    for (int a = 0; a < 64; ++a) {
        u32 w = p[(size_t)a * 2048];
        s0 += bflo(w);
        s1 += bfhi(w);
    }
    *(float2*)(S + (size_t)b * 4096 + 2 * j) = make_float2(s0, s1);
}

// ------------------------------------------------------------ phi1 ----
// First phi: L1 = rank-1 (cg,cg) only; L2 MFMA (h hi-only); writes bf16 msgs.
__global__ __launch_bounds__(256) void phi1_kernel(
    const float* __restrict__ cgT,
    const float* __restrict__ w0, const float* __restrict__ b1,
    const u16* __restrict__ A2, const float* __restrict__ b2,
    u16* __restrict__ mOut)
{
    constexpr int SROW = 72;
    __shared__ __align__(16) u16 Xhi[64 * SROW];
    const int t = threadIdx.x;
    const u32 sb = blockIdx.x;
    const int lane = t & 63;
    const int wv = t >> 6;
    const int n16 = lane & 15, q4 = lane >> 4;

    f32x4 acc[4];
    {
        const float4 bv = *(const float4*)(b1 + 16 * wv + 4 * q4);
        const float4 w0v = *(const float4*)(w0 + 16 * wv + 4 * q4);
#pragma unroll
        for (int tt = 0; tt < 4; ++tt) {
            float cgv = cgT[(size_t)sb * 64 + 16 * tt + n16];
            acc[tt][0] = bv.x + w0v.x * cgv; acc[tt][1] = bv.y + w0v.y * cgv;
            acc[tt][2] = bv.z + w0v.z * cgv; acc[tt][3] = bv.w + w0v.w * cgv;
        }
    }
#pragma unroll
    for (int tt = 0; tt < 4; ++tt)
#pragma unroll
        for (int r = 0; r < 4; ++r) acc[tt][r] = fmaxf(acc[tt][r], 0.0f);
    post_users_regs(acc, wv);
    stage_h<SROW, 0, false>(acc, Xhi, nullptr, lane, wv);
    __syncthreads();

    f32x4 acc2[4];
    {
        const float4 bv = *(const float4*)(b2 + 16 * wv + 4 * q4);
#pragma unroll
        for (int tt = 0; tt < 4; ++tt) { acc2[tt][0] = bv.x; acc2[tt][1] = bv.y; acc2[tt][2] = bv.z; acc2[tt][3] = bv.w; }
    }
    mfma_layer<2, 0, SROW, 0>(A2, Xhi, nullptr, lane, wv, acc2);
    post_users_regs(acc2, wv);            // no relu (phi L2)

    __syncthreads();
#pragma unroll
    for (int tt = 0; tt < 4; ++tt) {
        u32 h01 = cvt2(acc2[tt][0], acc2[tt][1]);
        u32 h23 = cvt2(acc2[tt][2], acc2[tt][3]);
        int off = (16 * tt + n16) * 72 + 16 * wv + 4 * q4;
        *(uint2*)(Xhi + off) = make_uint2(h01, h23);
    }
    __syncthreads();
    u16* oM = mOut + (size_t)sb * 4096;
#pragma unroll
    for (int q = 0; q < 2; ++q) {
        int grp = q * 256 + t;
        int u = grp >> 3, c8 = (grp & 7) * 8;
        *(uint4*)(oM + u * 64 + c8) = *(const uint4*)(Xhi + u * 72 + c8);
    }
}

// ------------------------------------------------------------ fused ----
// [gamma_k ; phi_{k+1}] per (b,a) slab.
// KG = gamma L1 K (64 for gamma1 [cg|agg] + rank-1 cg; 128 for [r|agg]).
// Lo planes: r (cols 0..63) and gamma-h only. agg/phi hi-only.
template <int KG>
__global__ __launch_bounds__(256) void fused_kernel(
    const float* __restrict__ cgT,
    const u16* __restrict__ rInHi, const u16* __restrict__ rInLo,
    const u32* __restrict__ mIn, const float* __restrict__ Sin,
    const u16* __restrict__ A1g, const float* __restrict__ w0g,
    const float* __restrict__ b1g,
    const u16* __restrict__ A2g, const float* __restrict__ b2g,
    const u16* __restrict__ A1p, const float* __restrict__ w0p,
    const float* __restrict__ b1p,
    const u16* __restrict__ A2p, const float* __restrict__ b2p,
    u16* __restrict__ rOutHi, u16* __restrict__ rOutLo, u16* __restrict__ mOut)
{
    constexpr int SROW = 136;
    __shared__ __align__(16) u16 Xhi[64 * SROW];
    __shared__ __align__(16) u16 Xlo[64 * SROWL];
    const int t = threadIdx.x;
    const u32 sb = blockIdx.x;          // slab = (b_local, a)
    const u32 bloc = sb >> 6;
    const int lane = t & 63;
    const int wv = t >> 6;
    const int n16 = lane & 15, q4 = lane >> 4;

    // hoisted cg loads (used by gamma1 rank-1 and phi rank-1)
    float cgvv[4];
#pragma unroll
    for (int tt = 0; tt < 4; ++tt) cgvv[tt] = cgT[(size_t)sb * 64 + 16 * tt + n16];

    // ---- stage gamma inputs: r (KG==128) at cols 0..63, agg at KG-64 ----
    if constexpr (KG == 128) {
        const u16* rsH = rInHi + (size_t)sb * 4096;
        const u16* rsL = rInLo + (size_t)sb * 4096;
#pragma unroll
        for (int q = 0; q < 2; ++q) {
            int grp = q * 256 + t;
            int u = grp >> 3, c8 = (grp & 7) * 8;
            *(uint4*)(Xhi + u * SROW + c8) = *(const uint4*)(rsH + u * 64 + c8);
            *(uint4*)(Xlo + u * SROWL + c8) = *(const uint4*)(rsL + u * 64 + c8);
        }
    }
    stage_agg<SROW, KG - 64>(mIn + (size_t)sb * 2048, Sin + (size_t)bloc * 4096,
                             Xhi, t);
    __syncthreads();

    // ---- gamma layer 1 ----
    f32x4 acc[4];
    {
        const float4 bv = *(const float4*)(b1g + 16 * wv + 4 * q4);
#pragma unroll
        for (int tt = 0; tt < 4; ++tt) { acc[tt][0] = bv.x; acc[tt][1] = bv.y; acc[tt][2] = bv.z; acc[tt][3] = bv.w; }
    }
    if constexpr (KG == 64) {           // gamma1: feats = cg (rank-1)
        const float4 w0v = *(const float4*)(w0g + 16 * wv + 4 * q4);
#pragma unroll
        for (int tt = 0; tt < 4; ++tt) {
            acc[tt][0] += w0v.x * cgvv[tt]; acc[tt][1] += w0v.y * cgvv[tt];
            acc[tt][2] += w0v.z * cgvv[tt]; acc[tt][3] += w0v.w * cgvv[tt];
        }
    }
    mfma_layer<KG / 32, (KG == 128 ? 2 : 0), SROW, 0>(A1g, Xhi, Xlo, lane, wv, acc);
#pragma unroll
    for (int tt = 0; tt < 4; ++tt)
#pragma unroll
        for (int r = 0; r < 4; ++r) acc[tt][r] = fmaxf(acc[tt][r], 0.0f);
    post_users_regs(acc, wv);
    __syncthreads();                     // L1 B-reads done before h overwrite
    stage_h<SROW, 0, true>(acc, Xhi, Xlo, lane, wv);
    __syncthreads();

    // ---- gamma layer 2 -> r_k (h hi+lo) ----
    f32x4 acc2[4];
    {
        const float4 bv = *(const float4*)(b2g + 16 * wv + 4 * q4);
#pragma unroll
        for (int tt = 0; tt < 4; ++tt) { acc2[tt][0] = bv.x; acc2[tt][1] = bv.y; acc2[tt][2] = bv.z; acc2[tt][3] = bv.w; }
    }
    mfma_layer<2, 2, SROW, 0>(A2g, Xhi, Xlo, lane, wv, acc2);
#pragma unroll
    for (int tt = 0; tt < 4; ++tt)
#pragma unroll
        for (int r = 0; r < 4; ++r) acc2[tt][r] = fmaxf(acc2[tt][r], 0.0f);
    post_users_regs(acc2, wv);

    // ---- stage r_k into LDS cols 0..63; write r_k to HBM ----
    __syncthreads();                     // L2 B-reads done before r overwrite
    stage_h<SROW, 0, true>(acc2, Xhi, Xlo, lane, wv);
    __syncthreads();
    {
        u16* oH = rOutHi + (size_t)sb * 4096;
        u16* oL = rOutLo + (size_t)sb * 4096;
#pragma unroll
        for (int q = 0; q < 2; ++q) {
            int grp = q * 256 + t;
            int u = grp >> 3, c8 = (grp & 7) * 8;
            *(uint4*)(oH + u * 64 + c8) = *(const uint4*)(Xhi + u * SROW + c8);
            *(uint4*)(oL + u * 64 + c8) = *(const uint4*)(Xlo + u * SROWL + c8);
        }
    }

    // ---- phi layer 1: rank-1 cg + MFMA over r_k (LDS, hi-only) ----
    f32x4 acc3[4];
    {
        const float4 bv = *(const float4*)(b1p + 16 * wv + 4 * q4);
        const float4 w0v = *(const float4*)(w0p + 16 * wv + 4 * q4);
#pragma unroll
        for (int tt = 0; tt < 4; ++tt) {
            acc3[tt][0] = bv.x + w0v.x * cgvv[tt]; acc3[tt][1] = bv.y + w0v.y * cgvv[tt];
            acc3[tt][2] = bv.z + w0v.z * cgvv[tt]; acc3[tt][3] = bv.w + w0v.w * cgvv[tt];
        }
    }
    mfma_layer<2, 0, SROW, 0>(A1p, Xhi, nullptr, lane, wv, acc3);
#pragma unroll
    for (int tt = 0; tt < 4; ++tt)
#pragma unroll
        for (int r = 0; r < 4; ++r) acc3[tt][r] = fmaxf(acc3[tt][r], 0.0f);
    post_users_regs(acc3, wv);
    // cols 64..127 have no live readers
    stage_h<SROW, 64, false>(acc3, Xhi, nullptr, lane, wv);
    __syncthreads();

    // ---- phi layer 2 -> msgs_{k+1} (h hi-only) ----
    f32x4 acc4[4];
    {
        const float4 bv = *(const float4*)(b2p + 16 * wv + 4 * q4);
#pragma unroll
        for (int tt = 0; tt < 4; ++tt) { acc4[tt][0] = bv.x; acc4[tt][1] = bv.y; acc4[tt][2] = bv.z; acc4[tt][3] = bv.w; }
    }
    mfma_layer<2, 0, SROW, 64>(A2p, Xhi, nullptr, lane, wv, acc4);
    post_users_regs(acc4, wv);            // no relu (phi L2)

    __syncthreads();
#pragma unroll
    for (int tt = 0; tt < 4; ++tt) {
        u32 h01 = cvt2(acc4[tt][0], acc4[tt][1]);
        u32 h23 = cvt2(acc4[tt][2], acc4[tt][3]);
        int off = (16 * tt + n16) * 72 + 16 * wv + 4 * q4;
        *(uint2*)(Xhi + off) = make_uint2(h01, h23);
    }
    __syncthreads();
    u16* oM = mOut + (size_t)sb * 4096;
#pragma unroll
    for (int q = 0; q < 2; ++q) {
        int grp = q * 256 + t;
        int u = grp >> 3, c8 = (grp & 7) * 8;
        *(uint4*)(oM + u * 64 + c8) = *(const uint4*)(Xhi + u * 72 + c8);
    }
}

// ------------------------------------------------------------ gamma5 ----
// Final gamma: [r | agg] K=128 L1 (r lo, agg hi-only); L2 = 1-row dot.
__global__ __launch_bounds__(256) void final_kernel(
    const u16* __restrict__ rInHi, const u16* __restrict__ rInLo,
    const u32* __restrict__ mIn, const float* __restrict__ Sin,
    const u16* __restrict__ A1, const float* __restrict__ b1,
    const float* __restrict__ w2raw, const float* __restrict__ b2raw,
    float* __restrict__ outF)
{
    constexpr int SROW = 136;
    __shared__ __align__(16) u16 Xhi[64 * SROW];
    __shared__ __align__(16) u16 Xlo[64 * SROWL];
    __shared__ float part[4][64];
    const int t = threadIdx.x;
    const u32 sb = blockIdx.x;
    const u32 bloc = sb >> 6;
    const int lane = t & 63;
    const int wv = t >> 6;
    const int n16 = lane & 15, q4 = lane >> 4;

    {
        const u16* rsH = rInHi + (size_t)sb * 4096;
        const u16* rsL = rInLo + (size_t)sb * 4096;
#pragma unroll
        for (int q = 0; q < 2; ++q) {
            int grp = q * 256 + t;
            int u = grp >> 3, c8 = (grp & 7) * 8;
            *(uint4*)(Xhi + u * SROW + c8) = *(const uint4*)(rsH + u * 64 + c8);
            *(uint4*)(Xlo + u * SROWL + c8) = *(const uint4*)(rsL + u * 64 + c8);
        }
    }
    stage_agg<SROW, 64>(mIn + (size_t)sb * 2048, Sin + (size_t)bloc * 4096,
                        Xhi, t);
    __syncthreads();

    f32x4 acc[4];
    {
        const float4 bv = *(const float4*)(b1 + 16 * wv + 4 * q4);
#pragma unroll
        for (int tt = 0; tt < 4; ++tt) { acc[tt][0] = bv.x; acc[tt][1] = bv.y; acc[tt][2] = bv.z; acc[tt][3] = bv.w; }
    }
    mfma_layer<4, 2, SROW, 0>(A1, Xhi, Xlo, lane, wv, acc);
#pragma unroll
    for (int tt = 0; tt < 4; ++tt)
#pragma unroll
        for (int r = 0; r < 4; ++r) acc[tt][r] = fmaxf(acc[tt][r], 0.0f);
    post_users_regs(acc, wv);
    __syncthreads();
    stage_h<SROW, 0, true>(acc, Xhi, Xlo, lane, wv);
    __syncthreads();

    const int cb2 = 16 * wv;
    const u16* hr = Xhi + lane * SROW + cb2;
    const u16* lr = Xlo + lane * SROWL + cb2;
    bf16x8 h0 = *(const bf16x8*)hr;
    bf16x8 h1 = *(const bf16x8*)(hr + 8);
    bf16x8 l0 = *(const bf16x8*)lr;
    bf16x8 l1 = *(const bf16x8*)(lr + 8);
    float sum = 0.0f;
#pragma unroll
    for (int j = 0; j < 8; ++j) {
        float v0 = bflo((u32)(u16)h0[j]) + bflo((u32)(u16)l0[j]);
        float v1 = bflo((u32)(u16)h1[j]) + bflo((u32)(u16)l1[j]);
        sum += w2raw[cb2 + j] * v0;
        sum += w2raw[cb2 + 8 + j] * v1;
    }
    part[wv][lane] = sum;
    __syncthreads();
    if (t < 64) {
        float o = b2raw[0] + part[0][t] + part[1][t] + part[2][t] + part[3][t];
        outF[((size_t)bloc * 64 + t) * 64 + (sb & 63)] = o;
    }
}

// -------------------------------------------------------------- launch ----
extern "C" void kernel_launch(void* const* d_in, const int* in_sizes, int n_in,
                              void* d_out, int out_size, void* d_ws, size_t ws_size,
                              hipStream_t stream) {
    const float* cg      = (const float*)d_in[0];
    const float* phi1_W1 = (const float*)d_in[1];
    const float* phi1_b1 = (const float*)d_in[2];
    const float* phi1_W2 = (const float*)d_in[3];
    const float* phi1_b2 = (const float*)d_in[4];
    const float* phiK_W1 = (const float*)d_in[5];
    const float* phiK_b1 = (const float*)d_in[6];
    const float* phiK_W2 = (const float*)d_in[7];
    const float* phiK_b2 = (const float*)d_in[8];
    const float* g1_W1   = (const float*)d_in[9];
    const float* g1_b1   = (const float*)d_in[10];
    const float* g1_W2   = (const float*)d_in[11];
    const float* g1_b2   = (const float*)d_in[12];
    const float* gK_W1   = (const float*)d_in[13];
    const float* gK_b1   = (const float*)d_in[14];
    const float* gK_W2   = (const float*)d_in[15];
    const float* gK_b2   = (const float*)d_in[16];
    const float* g5_W1   = (const float*)d_in[17];
    const float* g5_b1   = (const float*)d_in[18];
    const float* g5_W2   = (const float*)d_in[19];
    const float* g5_b2   = (const float*)d_in[20];
    (void)in_sizes; (void)n_in; (void)out_size;

    // Footprint (bytes): rHi/rLo/msgs = 3*BC*524288, S = BC*16384,
    // cgT = 2 MB, Apack = 360448, w0s tiny.
    int BC = 128;
    while (BC > 4 && (size_t)BC * 1589248 + 2461696 > ws_size) BC >>= 1;
    const int NC = 128 / BC;

    u16*   rHi  = (u16*)d_ws;
    u16*   rLo  = rHi + (size_t)BC * 262144;
    u16*   msgs = rLo + (size_t)BC * 262144;
    float* S    = (float*)(msgs + (size_t)BC * 262144);
    float* cgT  = S + (size_t)BC * 4096;
    u16*   Apack = (u16*)(cgT + 524288);
    float* w0s  = (float*)(Apack + 180224);
    float* out  = (float*)d_out;

    prep_kernel<<<354 + 2048, 256, 0, stream>>>(cg, cgT, Apack, w0s,
        phi1_W1, phi1_W2, phiK_W1, phiK_W2, g1_W1, g1_W2, gK_W1, gK_W2, g5_W1);

    const int nblk = BC * 64;
    const int rblk = BC * 8;

    for (int c = 0; c < NC; ++c) {
        const float* cgTc = cgT + (size_t)c * BC * 4096;
        float* outc = out + (size_t)c * BC * 4096;

        // phi1 -> msgs
        phi1_kernel<<<nblk, 256, 0, stream>>>(cgTc, w0s, phi1_b1,
            Apack + 0, phi1_b2, msgs);
        reduce_kernel<<<rblk, 256, 0, stream>>>((const u32*)msgs, S);

        // [gamma1 + phiK0] -> r, msgs
        fused_kernel<64><<<nblk, 256, 0, stream>>>(cgTc, nullptr, nullptr,
            (const u32*)msgs, S,
            Apack + 73728, w0s + 320, g1_b1, Apack + 81920, g1_b2,
            Apack + 8192, w0s + 64, phiK_b1, Apack + 40960, phiK_b2,
            rHi, rLo, msgs);
        reduce_kernel<<<rblk, 256, 0, stream>>>((const u32*)msgs, S);

        // [gammaK[j] + phiK[j+1]] for j = 0..2
        for (int j = 0; j < 3; ++j) {
            fused_kernel<128><<<nblk, 256, 0, stream>>>(cgTc, rHi, rLo,
                (const u32*)msgs, S,
                Apack + 90112 + (size_t)j * 16384, nullptr, gK_b1 + j * 64,
                Apack + 139264 + (size_t)j * 8192, gK_b2 + j * 64,
                Apack + 8192 + (size_t)(j + 1) * 8192, w0s + 64 + (j + 1) * 64,
                phiK_b1 + (j + 1) * 64,
                Apack + 40960 + (size_t)(j + 1) * 8192, phiK_b2 + (j + 1) * 64,
                rHi, rLo, msgs);
            reduce_kernel<<<rblk, 256, 0, stream>>>((const u32*)msgs, S);
        }

        // gamma5 -> out
        final_kernel<<<nblk, 256, 0, stream>>>(rHi, rLo, (const u32*)msgs, S,
            Apack + 163840, g5_b1, g5_W2, g5_b2, outc);
    }
}

// Round 8
// 541.531 us; speedup vs baseline: 5.0494x; 1.1367x over previous
//
#include <hip/hip_runtime.h>

// GNN_19971597927185 — MFMA bf16, fused [gamma_k + phi_{k+1}].
// B=128, U=64, A=64. One workgroup (4 waves) per (b,a) fiber; wave wv owns
// output rows [16wv,16wv+16), 4 col-tiles over u.
// Round 8: ALL activations hi-only bf16 (weights keep hi/lo split — 2-term
// MFMA: Ah*Bh + Al*Bh). Rationale: weights are 0.05-scaled => per-layer gain
// ~0.4, activation quant noise attenuates 0.16x per block; measured absmax
// has sat at the 1.22e-4 comparison floor through every previous precision
// drop. Xlo eliminated: LDS 26.6->17.4 KB, B-side ds_reads -29%, r HBM
// round-trip halves.

typedef __attribute__((ext_vector_type(8))) short bf16x8;
typedef __attribute__((ext_vector_type(4))) float f32x4;
typedef unsigned int u32;
typedef unsigned short u16;

__device__ __forceinline__ u32 bf16_rne(float x) {
    u32 u = __float_as_uint(x);
    return (u + 0x7fffu + ((u >> 16) & 1u)) >> 16;
}
__device__ __forceinline__ float bflo(u32 w) { return __uint_as_float(w << 16); }
__device__ __forceinline__ float bfhi(u32 w) { return __uint_as_float(w & 0xffff0000u); }

// Pack two f32 -> packed bf16x2 (a low 16, b high 16), RNE.
__device__ __forceinline__ u32 cvt2(float a, float b) {
#if __has_builtin(__builtin_amdgcn_cvt_pk_bf16_f32)
    auto p = __builtin_amdgcn_cvt_pk_bf16_f32(a, b);
    u32 w; __builtin_memcpy(&w, &p, 4);
    return w;
#else
    return bf16_rne(a) | (bf16_rne(b) << 16);
#endif
}

// DPP lane move within 16-lane row.
template <int CTRL>
__device__ __forceinline__ float dpp_mov(float v) {
    int x = __builtin_amdgcn_update_dpp(0, __float_as_int(v), CTRL, 0xF, 0xF, true);
    return __int_as_float(x);
}
// Sum across the 16-lane row (all lanes get the sum). VALU-only.
__device__ __forceinline__ float row16_sum(float s) {
    s += dpp_mov<0xB1>(s);    // quad_perm xor1
    s += dpp_mov<0x4E>(s);    // quad_perm xor2
    s += dpp_mov<0x141>(s);   // row_half_mirror
    s += dpp_mov<0x140>(s);   // row_mirror
    return s;
}

// ---------------------------------------------------------------- prep ----
__global__ __launch_bounds__(256) void prep_kernel(
    const float* __restrict__ cg, float* __restrict__ cgT,
    u16* __restrict__ packs, float* __restrict__ w0s,
    const float* __restrict__ phi1_W1, const float* __restrict__ phi1_W2,
    const float* __restrict__ phiK_W1, const float* __restrict__ phiK_W2,
    const float* __restrict__ g1_W1,   const float* __restrict__ g1_W2,
    const float* __restrict__ gK_W1,   const float* __restrict__ gK_W2,
    const float* __restrict__ g5_W1)
{
    const int bid = blockIdx.x;
    const int t = threadIdx.x;
    if (bid < 352) {
        int tid = bid * 256 + t;          // 0..90111 weight elements
        int layer, rem, nch;
        if (tid < 57344) { layer = tid >> 12; rem = tid & 4095; nch = 2; }
        else { layer = 14 + ((tid - 57344) >> 13); rem = (tid - 57344) & 8191; nch = 4; }
        const float* src; int stride, colOff; size_t dstBase;
        switch (layer) {
            case 0:  src = phi1_W2;                      stride = 64;  colOff = 0; dstBase = 0; break;
            case 1: case 2: case 3: case 4: {
                int k = layer - 1; src = phiK_W1 + k * 4160; stride = 65; colOff = 1;
                dstBase = 8192 + (size_t)k * 8192; break; }
            case 5: case 6: case 7: case 8: {
                int k = layer - 5; src = phiK_W2 + k * 4096; stride = 64; colOff = 0;
                dstBase = 40960 + (size_t)k * 8192; break; }
            case 9:  src = g1_W1;                        stride = 65;  colOff = 1; dstBase = 73728; break;
            case 10: src = g1_W2;                        stride = 64;  colOff = 0; dstBase = 81920; break;
            case 11: case 12: case 13: {
                int k = layer - 11; src = gK_W2 + k * 4096; stride = 64; colOff = 0;
                dstBase = 139264 + (size_t)k * 8192; break; }
            case 14: case 15: case 16: {
                int k = layer - 14; src = gK_W1 + k * 8192; stride = 128; colOff = 0;
                dstBase = 90112 + (size_t)k * 16384; break; }
            default: src = g5_W1;                        stride = 128; colOff = 0; dstBase = 163840; break;
        }
        int j = rem & 7;
        int lane = (rem >> 3) & 63;
        int rc = rem >> 9;                 // rb*nch + ch
        int rb = rc / nch;
        int ch = rc - rb * nch;
        int o = 16 * rb + (lane & 15);
        int c = colOff + ch * 32 + (lane >> 4) * 8 + j;
        float wv = src[o * stride + c];
        u32 hb = bf16_rne(wv);
        u32 lb = bf16_rne(wv - bflo(hb));
        size_t base = dstBase + (size_t)rc * 1024 + lane * 8 + j;
        packs[base] = (u16)hb;
        packs[base + 512] = (u16)lb;
    } else if (bid < 354) {
        int i = (bid - 352) * 256 + t;
        if (i < 64)       w0s[i] = phi1_W1[i * 2] + phi1_W1[i * 2 + 1];
        else if (i < 320) { int k = (i - 64) >> 6; int o = (i - 64) & 63; w0s[i] = phiK_W1[k * 4160 + o * 65]; }
        else if (i < 384) { int o = i - 320; w0s[i] = g1_W1[o * 65]; }
    } else {
        int idx = (bid - 354) * 256 + t;   // (b, a, u)
        int b = idx >> 12;
        int u = idx & 63;
        cgT[idx] = cg[((b << 6) + u) * 64 + ((idx >> 6) & 63)];
    }
}

// -------------------------------------------------------- MFMA helpers ----
// 2-term MFMA: Ah*Bh + Al*Bh (weight hi/lo split, activation hi-only).
// CB: column offset of B in Xhi.
template <int NCH, int SROW, int CB>
__device__ __forceinline__ void mfma_layer(const u16* __restrict__ A,
                                           const u16* Xhi,
                                           int lane, int wv, f32x4 acc[4]) {
    const int n16 = lane & 15, q4 = lane >> 4;
#pragma unroll
    for (int ch = 0; ch < NCH; ++ch) {
        bf16x8 Ah = *(const bf16x8*)(A + ((size_t)(wv * NCH + ch) * 2) * 512 + lane * 8);
        bf16x8 Al = *(const bf16x8*)(A + ((size_t)(wv * NCH + ch) * 2 + 1) * 512 + lane * 8);
#pragma unroll
        for (int tt = 0; tt < 4; ++tt) {
            int boff = (16 * tt + n16) * SROW + CB + ch * 32 + q4 * 8;
            bf16x8 Bh = *(const bf16x8*)(Xhi + boff);
            acc[tt] = __builtin_amdgcn_mfma_f32_16x16x32_bf16(Ah, Bh, acc[tt], 0, 0, 0);
            acc[tt] = __builtin_amdgcn_mfma_f32_16x16x32_bf16(Al, Bh, acc[tt], 0, 0, 0);
        }
    }
}

// post_users on C-layout accs: rowsum over u (4 tiles + 16-lane row via DPP).
__device__ __forceinline__ void post_users_regs(f32x4 acc[4], int wv) {
    constexpr float inv63 = 1.0f / 63.0f;
#pragma unroll
    for (int r = 0; r < 4; ++r) {
        float s = row16_sum(acc[0][r] + acc[1][r] + acc[2][r] + acc[3][r]);
        if (wv >= 2) {      // rows >= 32: aggregated half (wave-uniform branch)
#pragma unroll
            for (int tt = 0; tt < 4; ++tt) acc[tt][r] = (s - acc[tt][r]) * inv63;
        }
    }
}

// Stage C-layout acc into Xhi cols [CB,CB+64) (stride SROW), bf16 hi.
template <int SROW, int CB>
__device__ __forceinline__ void stage_h(const f32x4 acc[4], u16* Xhi,
                                        int lane, int wv) {
    const int n16 = lane & 15, q4 = lane >> 4;
#pragma unroll
    for (int tt = 0; tt < 4; ++tt) {
        u32 h01 = cvt2(acc[tt][0], acc[tt][1]);
        u32 h23 = cvt2(acc[tt][2], acc[tt][3]);
        int off = (16 * tt + n16) * SROW + CB + 16 * wv + 4 * q4;
        *(uint2*)(Xhi + off) = make_uint2(h01, h23);
    }
}

// Stage agg = (S - msgs)/63 into Xhi cols [CB, CB+64).
template <int SROW, int CB>
__device__ __forceinline__ void stage_agg(const u32* __restrict__ ms,
                                          const float* __restrict__ Ss,
                                          u16* Xhi, int t) {
    constexpr float inv63 = 1.0f / 63.0f;
#pragma unroll
    for (int q = 0; q < 4; ++q) {
        int grp = q * 256 + t;
        int u = grp >> 4, c4 = (grp & 15) * 4;
        uint2 mw = *(const uint2*)(ms + u * 32 + (c4 >> 1));
        float4 sv = *(const float4*)(Ss + u * 64 + c4);
        float a0 = (sv.x - bflo(mw.x)) * inv63;
        float a1 = (sv.y - bfhi(mw.x)) * inv63;
        float a2 = (sv.z - bflo(mw.y)) * inv63;
        float a3 = (sv.w - bfhi(mw.y)) * inv63;
        int off = u * SROW + CB + c4;
        *(uint2*)(Xhi + off) = make_uint2(cvt2(a0, a1), cvt2(a2, a3));
    }
}

// -------------------------------------------------------------- reduce ----
// S[b][u][c] (fp32) = sum_a msgs[b,a][u][c] (bf16). Thread = one u32 (2 c's).
__global__ __launch_bounds__(256) void reduce_kernel(
    const u32* __restrict__ msgs, float* __restrict__ S)
{
    int idx = blockIdx.x * 256 + threadIdx.x;   // b*2048 + j
    int b = idx >> 11;
    int j = idx & 2047;
    const u32* p = msgs + (size_t)b * 131072 + j;
    float s0 = 0.0f, s1 = 0.0f;
#pragma unroll 8
    for (int a = 0; a < 64; ++a) {
        u32 w = p[(size_t)a * 2048];
        s0 += bflo(w);
        s1 += bfhi(w);
    }
    *(float2*)(S + (size_t)b * 4096 + 2 * j) = make_float2(s0, s1);
}

// ------------------------------------------------------------ phi1 ----
// First phi: L1 = rank-1 (cg,cg) only; L2 MFMA; writes bf16 msgs.
__global__ __launch_bounds__(256) void phi1_kernel(
    const float* __restrict__ cgT,
    const float* __restrict__ w0, const float* __restrict__ b1,
    const u16* __restrict__ A2, const float* __restrict__ b2,
    u16* __restrict__ mOut)
{
    constexpr int SROW = 72;
    __shared__ __align__(16) u16 Xhi[64 * SROW];
    const int t = threadIdx.x;
    const u32 sb = blockIdx.x;
    const int lane = t & 63;
    const int wv = t >> 6;
    const int n16 = lane & 15, q4 = lane >> 4;

    f32x4 acc[4];
    {
        const float4 bv = *(const float4*)(b1 + 16 * wv + 4 * q4);
        const float4 w0v = *(const float4*)(w0 + 16 * wv + 4 * q4);
#pragma unroll
        for (int tt = 0; tt < 4; ++tt) {
            float cgv = cgT[(size_t)sb * 64 + 16 * tt + n16];
            acc[tt][0] = bv.x + w0v.x * cgv; acc[tt][1] = bv.y + w0v.y * cgv;
            acc[tt][2] = bv.z + w0v.z * cgv; acc[tt][3] = bv.w + w0v.w * cgv;
        }
    }
#pragma unroll
    for (int tt = 0; tt < 4; ++tt)
#pragma unroll
        for (int r = 0; r < 4; ++r) acc[tt][r] = fmaxf(acc[tt][r], 0.0f);
    post_users_regs(acc, wv);
    stage_h<SROW, 0>(acc, Xhi, lane, wv);
    __syncthreads();

    f32x4 acc2[4];
    {
        const float4 bv = *(const float4*)(b2 + 16 * wv + 4 * q4);
#pragma unroll
        for (int tt = 0; tt < 4; ++tt) { acc2[tt][0] = bv.x; acc2[tt][1] = bv.y; acc2[tt][2] = bv.z; acc2[tt][3] = bv.w; }
    }
    mfma_layer<2, SROW, 0>(A2, Xhi, lane, wv, acc2);
    post_users_regs(acc2, wv);            // no relu (phi L2)

    __syncthreads();
    stage_h<72, 0>(acc2, Xhi, lane, wv);
    __syncthreads();
    u16* oM = mOut + (size_t)sb * 4096;
#pragma unroll
    for (int q = 0; q < 2; ++q) {
        int grp = q * 256 + t;
        int u = grp >> 3, c8 = (grp & 7) * 8;
        *(uint4*)(oM + u * 64 + c8) = *(const uint4*)(Xhi + u * 72 + c8);
    }
}

// ------------------------------------------------------------ fused ----
// [gamma_k ; phi_{k+1}] per (b,a) slab.
// KG = gamma L1 K (64 for gamma1 [cg|agg] + rank-1 cg; 128 for [r|agg]).
// All activations bf16 hi-only. Writes r_k and msgs_{k+1}.
template <int KG>
__global__ __launch_bounds__(256) void fused_kernel(
    const float* __restrict__ cgT,
    const u16* __restrict__ rIn,
    const u32* __restrict__ mIn, const float* __restrict__ Sin,
    const u16* __restrict__ A1g, const float* __restrict__ w0g,
    const float* __restrict__ b1g,
    const u16* __restrict__ A2g, const float* __restrict__ b2g,
    const u16* __restrict__ A1p, const float* __restrict__ w0p,
    const float* __restrict__ b1p,
    const u16* __restrict__ A2p, const float* __restrict__ b2p,
    u16* __restrict__ rOut, u16* __restrict__ mOut)
{
    constexpr int SROW = 136;
    __shared__ __align__(16) u16 Xhi[64 * SROW];
    const int t = threadIdx.x;
    const u32 sb = blockIdx.x;          // slab = (b_local, a)
    const u32 bloc = sb >> 6;
    const int lane = t & 63;
    const int wv = t >> 6;
    const int n16 = lane & 15, q4 = lane >> 4;

    // hoisted cg loads (used by gamma1 rank-1 and phi rank-1)
    float cgvv[4];
#pragma unroll
    for (int tt = 0; tt < 4; ++tt) cgvv[tt] = cgT[(size_t)sb * 64 + 16 * tt + n16];

    // ---- stage gamma inputs: r (KG==128) at cols 0..63, agg at KG-64 ----
    if constexpr (KG == 128) {
        const u16* rs = rIn + (size_t)sb * 4096;
#pragma unroll
        for (int q = 0; q < 2; ++q) {
            int grp = q * 256 + t;
            int u = grp >> 3, c8 = (grp & 7) * 8;
            *(uint4*)(Xhi + u * SROW + c8) = *(const uint4*)(rs + u * 64 + c8);
        }
    }
    stage_agg<SROW, KG - 64>(mIn + (size_t)sb * 2048, Sin + (size_t)bloc * 4096,
                             Xhi, t);
    __syncthreads();

    // ---- gamma layer 1 ----
    f32x4 acc[4];
    {
        const float4 bv = *(const float4*)(b1g + 16 * wv + 4 * q4);
#pragma unroll
        for (int tt = 0; tt < 4; ++tt) { acc[tt][0] = bv.x; acc[tt][1] = bv.y; acc[tt][2] = bv.z; acc[tt][3] = bv.w; }
    }
    if constexpr (KG == 64) {           // gamma1: feats = cg (rank-1)
        const float4 w0v = *(const float4*)(w0g + 16 * wv + 4 * q4);
#pragma unroll
        for (int tt = 0; tt < 4; ++tt) {
            acc[tt][0] += w0v.x * cgvv[tt]; acc[tt][1] += w0v.y * cgvv[tt];
            acc[tt][2] += w0v.z * cgvv[tt]; acc[tt][3] += w0v.w * cgvv[tt];
        }
    }
    mfma_layer<KG / 32, SROW, 0>(A1g, Xhi, lane, wv, acc);
#pragma unroll
    for (int tt = 0; tt < 4; ++tt)
#pragma unroll
        for (int r = 0; r < 4; ++r) acc[tt][r] = fmaxf(acc[tt][r], 0.0f);
    post_users_regs(acc, wv);
    __syncthreads();                     // L1 B-reads done before h overwrite
    stage_h<SROW, 0>(acc, Xhi, lane, wv);
    __syncthreads();

    // ---- gamma layer 2 -> r_k ----
    f32x4 acc2[4];
    {
        const float4 bv = *(const float4*)(b2g + 16 * wv + 4 * q4);
#pragma unroll
        for (int tt = 0; tt < 4; ++tt) { acc2[tt][0] = bv.x; acc2[tt][1] = bv.y; acc2[tt][2] = bv.z; acc2[tt][3] = bv.w; }
    }
    mfma_layer<2, SROW, 0>(A2g, Xhi, lane, wv, acc2);
#pragma unroll
    for (int tt = 0; tt < 4; ++tt)
#pragma unroll
        for (int r = 0; r < 4; ++r) acc2[tt][r] = fmaxf(acc2[tt][r], 0.0f);
    post_users_regs(acc2, wv);

    // ---- stage r_k into LDS cols 0..63; write r_k to HBM ----
    __syncthreads();                     // L2 B-reads done before r overwrite
    stage_h<SROW, 0>(acc2, Xhi, lane, wv);
    __syncthreads();
    {
        u16* oH = rOut + (size_t)sb * 4096;
#pragma unroll
        for (int q = 0; q < 2; ++q) {
            int grp = q * 256 + t;
            int u = grp >> 3, c8 = (grp & 7) * 8;
            *(uint4*)(oH + u * 64 + c8) = *(const uint4*)(Xhi + u * SROW + c8);
        }
    }

    // ---- phi layer 1: rank-1 cg + MFMA over r_k (LDS) ----
    f32x4 acc3[4];
    {
        const float4 bv = *(const float4*)(b1p + 16 * wv + 4 * q4);
        const float4 w0v = *(const float4*)(w0p + 16 * wv + 4 * q4);
#pragma unroll
        for (int tt = 0; tt < 4; ++tt) {
            acc3[tt][0] = bv.x + w0v.x * cgvv[tt]; acc3[tt][1] = bv.y + w0v.y * cgvv[tt];
            acc3[tt][2] = bv.z + w0v.z * cgvv[tt]; acc3[tt][3] = bv.w + w0v.w * cgvv[tt];
        }
    }
    mfma_layer<2, SROW, 0>(A1p, Xhi, lane, wv, acc3);
#pragma unroll
    for (int tt = 0; tt < 4; ++tt)
#pragma unroll
        for (int r = 0; r < 4; ++r) acc3[tt][r] = fmaxf(acc3[tt][r], 0.0f);
    post_users_regs(acc3, wv);
    // cols 64..127 have no live readers (agg dead after gamma L1)
    stage_h<SROW, 64>(acc3, Xhi, lane, wv);
    __syncthreads();

    // ---- phi layer 2 -> msgs_{k+1} ----
    f32x4 acc4[4];
    {
        const float4 bv = *(const float4*)(b2p + 16 * wv + 4 * q4);
#pragma unroll
        for (int tt = 0; tt < 4; ++tt) { acc4[tt][0] = bv.x; acc4[tt][1] = bv.y; acc4[tt][2] = bv.z; acc4[tt][3] = bv.w; }
    }
    mfma_layer<2, SROW, 64>(A2p, Xhi, lane, wv, acc4);
    post_users_regs(acc4, wv);            // no relu (phi L2)

    __syncthreads();
#pragma unroll
    for (int tt = 0; tt < 4; ++tt) {
        u32 h01 = cvt2(acc4[tt][0], acc4[tt][1]);
        u32 h23 = cvt2(acc4[tt][2], acc4[tt][3]);
        int off = (16 * tt + n16) * 72 + 16 * wv + 4 * q4;
        *(uint2*)(Xhi + off) = make_uint2(h01, h23);
    }
    __syncthreads();
    u16* oM = mOut + (size_t)sb * 4096;
#pragma unroll
    for (int q = 0; q < 2; ++q) {
        int grp = q * 256 + t;
        int u = grp >> 3, c8 = (grp & 7) * 8;
        *(uint4*)(oM + u * 64 + c8) = *(const uint4*)(Xhi + u * 72 + c8);
    }
}

// ------------------------------------------------------------ gamma5 ----
// Final gamma: [r | agg] K=128 L1; L2 = 1-row dot; writes fp32 out.
__global__ __launch_bounds__(256) void final_kernel(
    const u16* __restrict__ rIn,
    const u32* __restrict__ mIn, const float* __restrict__ Sin,
    const u16* __restrict__ A1, const float* __restrict__ b1,
    const float* __restrict__ w2raw, const float* __restrict__ b2raw,
    float* __restrict__ outF)
{
    constexpr int SROW = 136;
    __shared__ __align__(16) u16 Xhi[64 * SROW];
    __shared__ float part[4][64];
    const int t = threadIdx.x;
    const u32 sb = blockIdx.x;
    const u32 bloc = sb >> 6;
    const int lane = t & 63;
    const int wv = t >> 6;
    const int n16 = lane & 15, q4 = lane >> 4;

    {
        const u16* rs = rIn + (size_t)sb * 4096;
#pragma unroll
        for (int q = 0; q < 2; ++q) {
            int grp = q * 256 + t;
            int u = grp >> 3, c8 = (grp & 7) * 8;
            *(uint4*)(Xhi + u * SROW + c8) = *(const uint4*)(rs + u * 64 + c8);
        }
    }
    stage_agg<SROW, 64>(mIn + (size_t)sb * 2048, Sin + (size_t)bloc * 4096,
                        Xhi, t);
    __syncthreads();

    f32x4 acc[4];
    {
        const float4 bv = *(const float4*)(b1 + 16 * wv + 4 * q4);
#pragma unroll
        for (int tt = 0; tt < 4; ++tt) { acc[tt][0] = bv.x; acc[tt][1] = bv.y; acc[tt][2] = bv.z; acc[tt][3] = bv.w; }
    }
    mfma_layer<4, SROW, 0>(A1, Xhi, lane, wv, acc);
#pragma unroll
    for (int tt = 0; tt < 4; ++tt)
#pragma unroll
        for (int r = 0; r < 4; ++r) acc[tt][r] = fmaxf(acc[tt][r], 0.0f);
    post_users_regs(acc, wv);
    __syncthreads();
    stage_h<SROW, 0>(acc, Xhi, lane, wv);
    __syncthreads();

    const int cb2 = 16 * wv;
    const u16* hr = Xhi + lane * SROW + cb2;
    bf16x8 h0 = *(const bf16x8*)hr;
    bf16x8 h1 = *(const bf16x8*)(hr + 8);
    float sum = 0.0f;
#pragma unroll
    for (int j = 0; j < 8; ++j) {
        sum += w2raw[cb2 + j] * bflo((u32)(u16)h0[j]);
        sum += w2raw[cb2 + 8 + j] * bflo((u32)(u16)h1[j]);
    }
    part[wv][lane] = sum;
    __syncthreads();
    if (t < 64) {
        float o = b2raw[0] + part[0][t] + part[1][t] + part[2][t] + part[3][t];
        outF[((size_t)bloc * 64 + t) * 64 + (sb & 63)] = o;
    }
}

// -------------------------------------------------------------- launch ----
extern "C" void kernel_launch(void* const* d_in, const int* in_sizes, int n_in,
                              void* d_out, int out_size, void* d_ws, size_t ws_size,
                              hipStream_t stream) {
    const float* cg      = (const float*)d_in[0];
    const float* phi1_W1 = (const float*)d_in[1];
    const float* phi1_b1 = (const float*)d_in[2];
    const float* phi1_W2 = (const float*)d_in[3];
    const float* phi1_b2 = (const float*)d_in[4];
    const float* phiK_W1 = (const float*)d_in[5];
    const float* phiK_b1 = (const float*)d_in[6];
    const float* phiK_W2 = (const float*)d_in[7];
    const float* phiK_b2 = (const float*)d_in[8];
    const float* g1_W1   = (const float*)d_in[9];
    const float* g1_b1   = (const float*)d_in[10];
    const float* g1_W2   = (const float*)d_in[11];
    const float* g1_b2   = (const float*)d_in[12];
    const float* gK_W1   = (const float*)d_in[13];
    const float* gK_b1   = (const float*)d_in[14];
    const float* gK_W2   = (const float*)d_in[15];
    const float* gK_b2   = (const float*)d_in[16];
    const float* g5_W1   = (const float*)d_in[17];
    const float* g5_b1   = (const float*)d_in[18];
    const float* g5_W2   = (const float*)d_in[19];
    const float* g5_b2   = (const float*)d_in[20];
    (void)in_sizes; (void)n_in; (void)out_size;

    // Footprint (bytes): rHi/msgs = 2*BC*524288, S = BC*16384,
    // cgT = 2 MB, Apack = 360448, w0s tiny.
    int BC = 128;
    while (BC > 4 && (size_t)BC * 1064960 + 2461696 > ws_size) BC >>= 1;
    const int NC = 128 / BC;

    u16*   rHi  = (u16*)d_ws;
    u16*   msgs = rHi + (size_t)BC * 262144;
    float* S    = (float*)(msgs + (size_t)BC * 262144);
    float* cgT  = S + (size_t)BC * 4096;
    u16*   Apack = (u16*)(cgT + 524288);
    float* w0s  = (float*)(Apack + 180224);
    float* out  = (float*)d_out;

    prep_kernel<<<354 + 2048, 256, 0, stream>>>(cg, cgT, Apack, w0s,
        phi1_W1, phi1_W2, phiK_W1, phiK_W2, g1_W1, g1_W2, gK_W1, gK_W2, g5_W1);

    const int nblk = BC * 64;
    const int rblk = BC * 8;

    for (int c = 0; c < NC; ++c) {
        const float* cgTc = cgT + (size_t)c * BC * 4096;
        float* outc = out + (size_t)c * BC * 4096;

        // phi1 -> msgs
        phi1_kernel<<<nblk, 256, 0, stream>>>(cgTc, w0s, phi1_b1,
            Apack + 0, phi1_b2, msgs);
        reduce_kernel<<<rblk, 256, 0, stream>>>((const u32*)msgs, S);

        // [gamma1 + phiK0] -> r, msgs
        fused_kernel<64><<<nblk, 256, 0, stream>>>(cgTc, nullptr,
            (const u32*)msgs, S,
            Apack + 73728, w0s + 320, g1_b1, Apack + 81920, g1_b2,
            Apack + 8192, w0s + 64, phiK_b1, Apack + 40960, phiK_b2,
            rHi, msgs);
        reduce_kernel<<<rblk, 256, 0, stream>>>((const u32*)msgs, S);

        // [gammaK[j] + phiK[j+1]] for j = 0..2
        for (int j = 0; j < 3; ++j) {
            fused_kernel<128><<<nblk, 256, 0, stream>>>(cgTc, rHi,
                (const u32*)msgs, S,
                Apack + 90112 + (size_t)j * 16384, nullptr, gK_b1 + j * 64,
                Apack + 139264 + (size_t)j * 8192, gK_b2 + j * 64,
                Apack + 8192 + (size_t)(j + 1) * 8192, w0s + 64 + (j + 1) * 64,
                phiK_b1 + (j + 1) * 64,
                Apack + 40960 + (size_t)(j + 1) * 8192, phiK_b2 + (j + 1) * 64,
                rHi, msgs);
            reduce_kernel<<<rblk, 256, 0, stream>>>((const u32*)msgs, S);
        }

        // gamma5 -> out
        final_kernel<<<nblk, 256, 0, stream>>>(rHi, (const u32*)msgs, S,
            Apack + 163840, g5_b1, g5_W2, g5_b2, outc);
    }
}